// Round 1
// baseline (1151.638 us; speedup 1.0000x reference)
//
#include <hip/hip_runtime.h>
#include <hip/hip_bf16.h>
#include <stdint.h>
#include <math.h>

// Problem constants
#define N_TOK 48000     // 32*1500
#define DIMS  256
#define KCB   2048
#define GAP_THR 2e-3f

// JAX threefry flavor: 1 = partitionable (JAX >= 0.4.30 default), 0 = legacy
#define JAX_PARTITIONABLE 1

// ---------------- Threefry-2x32 (matches jax._src.prng) ----------------
__device__ inline void tf2x32(uint32_t k0, uint32_t k1, uint32_t c0, uint32_t c1,
                              uint32_t& o0, uint32_t& o1) {
  uint32_t ks2 = k0 ^ k1 ^ 0x1BD11BDAu;
  uint32_t x0 = c0 + k0, x1 = c1 + k1;
#define TF_R(r) { x0 += x1; x1 = (x1 << (r)) | (x1 >> (32 - (r))); x1 ^= x0; }
  TF_R(13) TF_R(15) TF_R(26) TF_R(6)
  x0 += k1; x1 += ks2 + 1u;
  TF_R(17) TF_R(29) TF_R(16) TF_R(24)
  x0 += ks2; x1 += k0 + 2u;
  TF_R(13) TF_R(15) TF_R(26) TF_R(6)
  x0 += k0; x1 += k1 + 3u;
  TF_R(17) TF_R(29) TF_R(16) TF_R(24)
  x0 += k1; x1 += ks2 + 4u;
  TF_R(13) TF_R(15) TF_R(26) TF_R(6)
  x0 += ks2; x1 += k0 + 5u;
#undef TF_R
  o0 = x0; o1 = x1;
}

__device__ inline void get_round_key(int round, uint32_t& ka, uint32_t& kb) {
  const uint32_t b0 = 0u, b1 = 1u;  // jax.random.key(1) -> (0,1)
#if JAX_PARTITIONABLE
  uint32_t K1a, K1b, S1a, S1b;
  tf2x32(b0, b1, 0u, 0u, K1a, K1b);     // new key   = tf(base,(0,0))
  tf2x32(b0, b1, 0u, 1u, S1a, S1b);     // subkey    = tf(base,(0,1))
  if (round == 1) { ka = S1a; kb = S1b; return; }
  uint32_t K2a, K2b, S2a, S2b;
  tf2x32(K1a, K1b, 0u, 0u, K2a, K2b);
  tf2x32(K1a, K1b, 0u, 1u, S2a, S2b);
  ka = S2a; kb = S2b;
#else
  // legacy split: counts=[0,1,2,3] -> lanes (0,2),(1,3); key=(o0_A,o0_B), sub=(o1_A,o1_B)
  uint32_t a0, a1, c0, c1;
  tf2x32(b0, b1, 0u, 2u, a0, a1);
  tf2x32(b0, b1, 1u, 3u, c0, c1);
  uint32_t K1a = a0, K1b = c0, S1a = a1, S1b = c1;
  if (round == 1) { ka = S1a; kb = S1b; return; }
  tf2x32(K1a, K1b, 0u, 2u, a0, a1);
  tf2x32(K1a, K1b, 1u, 3u, c0, c1);
  ka = a1; kb = c1;
#endif
}

__device__ inline uint32_t gen_key(int round, uint32_t i) {
  uint32_t ka, kb, o0, o1;
  get_round_key(round, ka, kb);
#if JAX_PARTITIONABLE
  tf2x32(ka, kb, 0u, i, o0, o1);
  return o0 ^ o1;                         // 32-bit partitionable fold
#else
  // legacy: counts split in halves: bits[i<24000]=o0 of (i,i+24000); else o1
  if (i < 24000u) { tf2x32(ka, kb, i, i + 24000u, o0, o1); return o0; }
  tf2x32(ka, kb, i - 24000u, i, o0, o1); return o1;
#endif
}

// ---------------- e2[k] = sum(embed[k]^2) ----------------
__global__ void e2_kernel(const float* __restrict__ embed, float* __restrict__ e2) {
  int k = blockIdx.x * blockDim.x + threadIdx.x;
  if (k >= KCB) return;
  const float4* er = (const float4*)(embed + (size_t)k * DIMS);
  float s = 0.f;
  for (int c = 0; c < DIMS / 4; ++c) {
    float4 v = er[c];
    s = fmaf(v.x, v.x, s); s = fmaf(v.y, v.y, s);
    s = fmaf(v.z, v.z, s); s = fmaf(v.w, v.w, s);
  }
  e2[k] = s;
}

// ---------------- main distance top-2 (f32, register-tiled) ----------------
// score = 2*dot(x_n, e_k) - e2[k]  (x2 is row-constant: irrelevant for argmax)
// grid (375, 2): 128 n-rows per block, k-half per blockIdx.y. 256 thr = 16x16,
// per-thread 8n x 8k, d staged in 64-chunks. LDS ~70KB -> 2 blocks/CU.
__global__ __launch_bounds__(256, 2) void dist_topk(
    const float* __restrict__ x, const float* __restrict__ embed,
    const float* __restrict__ e2,
    float* __restrict__ pbest, float* __restrict__ psecond, int* __restrict__ pbestk)
{
  __shared__ __align__(16) float smem[2 * 128 * 68];
  float (*xs)[68] = (float(*)[68])smem;
  float (*es)[68] = (float(*)[68])(smem + 128 * 68);
  __shared__ float e2s[128];

  const int tid = threadIdx.x;
  const int tc = tid & 15, tr = tid >> 4;
  const int n0 = blockIdx.x * 128;
  const int half = blockIdx.y;

  float best[8], second[8]; int bestk[8];
#pragma unroll
  for (int i = 0; i < 8; ++i) { best[i] = -INFINITY; second[i] = -INFINITY; bestk[i] = 0; }

  const float4* xg = (const float4*)x;
  const float4* eg = (const float4*)embed;

#pragma unroll 1
  for (int kt = 0; kt < 8; ++kt) {
    const int k0 = half * 1024 + kt * 128;
    float acc[8][8];
#pragma unroll
    for (int i = 0; i < 8; ++i)
#pragma unroll
      for (int j = 0; j < 8; ++j) acc[i][j] = 0.f;

#pragma unroll 1
    for (int d0 = 0; d0 < DIMS; d0 += 64) {
      __syncthreads();
#pragma unroll
      for (int q = 0; q < 8; ++q) {
        int f = tid + q * 256;
        int r = f >> 4, c = f & 15;
        *(float4*)&xs[r][c * 4] = xg[(size_t)(n0 + r) * 64 + (d0 >> 2) + c];
        *(float4*)&es[r][c * 4] = eg[(size_t)(k0 + r) * 64 + (d0 >> 2) + c];
      }
      if (d0 == 0 && tid < 128) e2s[tid] = e2[k0 + tid];
      __syncthreads();
#pragma unroll 4
      for (int dq = 0; dq < 16; ++dq) {
        float4 xv[8], ev[8];
#pragma unroll
        for (int i = 0; i < 8; ++i) xv[i] = *(const float4*)&xs[tr + 16 * i][dq * 4];
#pragma unroll
        for (int j = 0; j < 8; ++j) ev[j] = *(const float4*)&es[tc + 16 * j][dq * 4];
#pragma unroll
        for (int i = 0; i < 8; ++i)
#pragma unroll
          for (int j = 0; j < 8; ++j) {
            acc[i][j] = fmaf(xv[i].x, ev[j].x, acc[i][j]);
            acc[i][j] = fmaf(xv[i].y, ev[j].y, acc[i][j]);
            acc[i][j] = fmaf(xv[i].z, ev[j].z, acc[i][j]);
            acc[i][j] = fmaf(xv[i].w, ev[j].w, acc[i][j]);
          }
      }
    }
    // fold this k-tile into running top-2 (ascending k within thread)
#pragma unroll
    for (int j = 0; j < 8; ++j) {
      float ee = e2s[tc + 16 * j];
      int kk = k0 + tc + 16 * j;
#pragma unroll
      for (int i = 0; i < 8; ++i) {
        float v = fmaf(2.f, acc[i][j], -ee);
        if (v > best[i]) { second[i] = best[i]; best[i] = v; bestk[i] = kk; }
        else if (v > second[i]) second[i] = v;
      }
    }
  }

  // cross-thread (tc) reduce via LDS (reuse smem)
  __syncthreads();
  float* redB = smem; float* redS = smem + 2048; int* redK = (int*)(smem + 4096);
#pragma unroll
  for (int i = 0; i < 8; ++i) {
    int r = tr + 16 * i;
    redB[r * 16 + tc] = best[i];
    redS[r * 16 + tc] = second[i];
    redK[r * 16 + tc] = bestk[i];
  }
  __syncthreads();
  if (tid < 128) {
    float b = -INFINITY, s = -INFINITY; int bk = 0x7fffffff;
    for (int t = 0; t < 16; ++t) {
      float bb = redB[tid * 16 + t], ss = redS[tid * 16 + t];
      int kk = redK[tid * 16 + t];
      if (bb > b) { s = fmaxf(b, ss); b = bb; bk = kk; }
      else { s = fmaxf(s, bb); if (bb == b && kk < bk) bk = kk; }
    }
    size_t o = (size_t)half * N_TOK + n0 + tid;
    pbest[o] = b; psecond[o] = s; pbestk[o] = bk;
  }
}

// ---------------- merge two k-halves -> ind, gap ----------------
__global__ void merge_halves(const float* __restrict__ pbest, const float* __restrict__ psecond,
                             const int* __restrict__ pbestk,
                             int* __restrict__ ind, float* __restrict__ gap) {
  int n = blockIdx.x * blockDim.x + threadIdx.x;
  if (n >= N_TOK) return;
  float b0 = pbest[n], s0 = psecond[n]; int k0 = pbestk[n];
  float b1 = pbest[N_TOK + n], s1 = psecond[N_TOK + n]; int k1 = pbestk[N_TOK + n];
  float b, s; int bk;
  if (b1 > b0)      { b = b1; s = fmaxf(b0, s1); bk = k1; }
  else if (b1 < b0) { b = b0; s = fmaxf(s0, b1); bk = k0; }
  else              { b = b0; s = b1; bk = k0; }   // tie -> smaller k (half0)
  ind[n] = bk; gap[n] = b - s;
}

// ---------------- f64 re-resolution of near-ties ----------------
__global__ void refine(const float* __restrict__ x, const float* __restrict__ embed,
                       const float* __restrict__ gap, int* __restrict__ ind) {
  const int n = blockIdx.x;
  if (gap[n] >= GAP_THR) return;
  __shared__ double xd[DIMS];
  __shared__ double rv[256];
  __shared__ int    rk[256];
  const int tid = threadIdx.x;
  xd[tid] = (double)x[(size_t)n * DIMS + tid];
  __syncthreads();
  double bb = -1e300; int bk = 0x7fffffff;
  for (int k = tid; k < KCB; k += 256) {
    const float* er = embed + (size_t)k * DIMS;
    double dot = 0.0, ee = 0.0;
    for (int d = 0; d < DIMS; d += 4) {
      float4 e4 = *(const float4*)(er + d);
      dot += xd[d + 0] * (double)e4.x + xd[d + 1] * (double)e4.y
           + xd[d + 2] * (double)e4.z + xd[d + 3] * (double)e4.w;
      ee  += (double)e4.x * e4.x + (double)e4.y * e4.y
           + (double)e4.z * e4.z + (double)e4.w * e4.w;
    }
    double v = 2.0 * dot - ee;
    if (v > bb || (v == bb && k < bk)) { bb = v; bk = k; }
  }
  rv[tid] = bb; rk[tid] = bk;
  __syncthreads();
  for (int s = 128; s > 0; s >>= 1) {
    if (tid < s) {
      double v2 = rv[tid + s]; int k2 = rk[tid + s];
      if (v2 > rv[tid] || (v2 == rv[tid] && k2 < rk[tid])) { rv[tid] = v2; rk[tid] = k2; }
    }
    __syncthreads();
  }
  if (tid == 0) ind[n] = rk[0];
}

// ---------------- quantize gather + codes + counts + embed_sum ----------------
__global__ void gather_scatter(const float* __restrict__ x, const float* __restrict__ embed,
                               const int* __restrict__ ind,
                               float* __restrict__ outq, float* __restrict__ outcodes,
                               float* __restrict__ counts, float* __restrict__ esum) {
  int idx = blockIdx.x * blockDim.x + threadIdx.x;   // over N_TOK*64 float4s
  if (idx >= N_TOK * 64) return;
  int n = idx >> 6, c = idx & 63;
  int k = ind[n];
  float4 e = ((const float4*)embed)[(size_t)k * 64 + c];
  ((float4*)outq)[idx] = e;
  float4 xv = ((const float4*)x)[idx];
  float* base = esum + (size_t)k * DIMS + c * 4;
  atomicAdd(base + 0, xv.x); atomicAdd(base + 1, xv.y);
  atomicAdd(base + 2, xv.z); atomicAdd(base + 3, xv.w);
  if (c == 0) { outcodes[n] = (float)k; atomicAdd(&counts[k], 1.0f); }
}

// ---------------- new_cluster_size + n-sum + expired ----------------
__global__ void ema_stats(const float* __restrict__ cs, const float* __restrict__ counts,
                          float* __restrict__ out_ncs, int* __restrict__ expired,
                          double* __restrict__ nsum) {
  __shared__ double sd[1024];
  int tid = threadIdx.x;
  double local = 0.0;
  for (int k = tid; k < KCB; k += 1024) {
    double v = 0.99 * (double)cs[k] + 0.01 * (double)counts[k];
    out_ncs[k] = (float)v;
    expired[k] = (v < 2.0) ? 1 : 0;
    local += v;
  }
  sd[tid] = local; __syncthreads();
  for (int s = 512; s > 0; s >>= 1) { if (tid < s) sd[tid] += sd[tid + s]; __syncthreads(); }
  if (tid == 0) nsum[0] = sd[0];
}

// ---------------- new_embed_avg + new_embed ----------------
__global__ void final_embed(const float* __restrict__ x, const float* __restrict__ cs,
                            const float* __restrict__ counts,
                            const float* __restrict__ eavg, const float* __restrict__ esum,
                            const int* __restrict__ expired, const double* __restrict__ nsum,
                            const uint32_t* __restrict__ perm,
                            float* __restrict__ out_eavg, float* __restrict__ out_ne) {
  int idx = blockIdx.x * blockDim.x + threadIdx.x;   // over KCB*64 float4s
  if (idx >= KCB * 64) return;
  int k = idx >> 6, c = idx & 63;
  float4 ea = ((const float4*)eavg)[idx];
  float4 es = ((const float4*)esum)[idx];
  double ax = 0.99 * (double)ea.x + 0.01 * (double)es.x;
  double ay = 0.99 * (double)ea.y + 0.01 * (double)es.y;
  double az = 0.99 * (double)ea.z + 0.01 * (double)es.z;
  double aw = 0.99 * (double)ea.w + 0.01 * (double)es.w;
  float4 nv; nv.x = (float)ax; nv.y = (float)ay; nv.z = (float)az; nv.w = (float)aw;
  ((float4*)out_eavg)[idx] = nv;
  float4 r;
  if (expired[k]) {
    r = ((const float4*)x)[(size_t)perm[k] * 64 + c];
  } else {
    double ncs = 0.99 * (double)cs[k] + 0.01 * (double)counts[k];
    double n = nsum[0];
    double sm = (ncs + 1e-5) / (n + 2048.0 * 1e-5) * n;
    r.x = (float)(ax / sm); r.y = (float)(ay / sm);
    r.z = (float)(az / sm); r.w = (float)(aw / sm);
  }
  ((float4*)out_ne)[idx] = r;
}

// ---------------- permutation pipeline (stable sort by random keys) ----------------
__global__ void keys_round(int round, uint32_t* __restrict__ keys,
                           uint32_t* __restrict__ vals_init, uint32_t* __restrict__ bcount) {
  int i = blockIdx.x * blockDim.x + threadIdx.x;
  if (i >= N_TOK) return;
  uint32_t key = gen_key(round, (uint32_t)i);
  keys[i] = key;
  if (vals_init) vals_init[i] = (uint32_t)i;
  atomicAdd(&bcount[key >> 21], 1u);
}

__global__ void scan2048(const uint32_t* __restrict__ in, uint32_t* __restrict__ out,
                         uint32_t* __restrict__ cursor_zero) {
  __shared__ uint32_t buf[2][2048];
  int t = threadIdx.x;   // 1024
  for (int q = 0; q < 2; ++q) buf[0][t + q * 1024] = in[t + q * 1024];
  cursor_zero[t] = 0; cursor_zero[t + 1024] = 0;
  __syncthreads();
  int src = 0;
  for (int off = 1; off < 2048; off <<= 1) {
    for (int q = 0; q < 2; ++q) {
      int i = t + q * 1024;
      uint32_t v = buf[src][i];
      if (i >= off) v += buf[src][i - off];
      buf[src ^ 1][i] = v;
    }
    src ^= 1; __syncthreads();
  }
  for (int q = 0; q < 2; ++q) {
    int i = t + q * 1024;
    out[i] = buf[src][i] - in[i];   // exclusive
  }
}

__global__ void scatter_buckets(const uint32_t* __restrict__ keys, const uint32_t* __restrict__ vals_in,
                                const uint32_t* __restrict__ bbase, uint32_t* __restrict__ cursor,
                                uint32_t* __restrict__ bkey, uint32_t* __restrict__ bval,
                                uint32_t* __restrict__ bpos) {
  int i = blockIdx.x * blockDim.x + threadIdx.x;
  if (i >= N_TOK) return;
  uint32_t k = keys[i];
  uint32_t b = k >> 21;
  uint32_t p = atomicAdd(&cursor[b], 1u);
  uint32_t s = bbase[b] + p;
  bkey[s] = k; bval[s] = vals_in[i]; bpos[s] = (uint32_t)i;
}

// exact stable rank within bucket by (key, original position) -> deterministic
__global__ void rank_buckets(const uint32_t* __restrict__ bkey, const uint32_t* __restrict__ bval,
                             const uint32_t* __restrict__ bpos, const uint32_t* __restrict__ bbase,
                             const uint32_t* __restrict__ bcount, uint32_t* __restrict__ out_vals) {
  int b = blockIdx.x;
  uint32_t base = bbase[b], cnt = bcount[b];
  for (uint32_t t = threadIdx.x; t < cnt; t += blockDim.x) {
    uint32_t k = bkey[base + t], p = bpos[base + t];
    uint32_t r = 0;
    for (uint32_t j = 0; j < cnt; ++j) {
      uint32_t kj = bkey[base + j], pj = bpos[base + j];
      r += (kj < k) | ((kj == k) & (pj < p));
    }
    out_vals[base + r] = bval[base + t];
  }
}

// ---------------- launch ----------------
extern "C" void kernel_launch(void* const* d_in, const int* in_sizes, int n_in,
                              void* d_out, int out_size, void* d_ws, size_t ws_size,
                              hipStream_t stream) {
  const float* x     = (const float*)d_in[0];
  const float* embed = (const float*)d_in[1];
  const float* cs    = (const float*)d_in[2];
  const float* eavg  = (const float*)d_in[3];

  float* out = (float*)d_out;
  float* outQ    = out;                  // 12,288,000
  float* outC    = out + 12288000;       // 48,000
  float* outNCS  = out + 12336000;       // 2,048
  float* outEAVG = out + 12338048;       // 524,288
  float* outNE   = out + 12862336;       // 524,288

  char* w = (char*)d_ws;
  int*      ind     = (int*)     (w + 0);        // 192000
  float*    gap     = (float*)   (w + 192000);   // 192000
  float*    e2      = (float*)   (w + 384000);   // 8192
  float*    counts  = (float*)   (w + 392192);   // 8192
  float*    esum    = (float*)   (w + 400384);   // 2097152
  double*   nsum    = (double*)  (w + 2497536);  // 256
  int*      expired = (int*)     (w + 2497792);  // 8192
  float*    pbest   = (float*)   (w + 2505984);  // 384000
  float*    psecond = (float*)   (w + 2889984);  // 384000
  int*      pbestk  = (int*)     (w + 3273984);  // 384000
  uint32_t* keys    = (uint32_t*)(w + 3657984);  // 192000
  uint32_t* valsA   = (uint32_t*)(w + 3849984);  // 192000
  uint32_t* bkey    = (uint32_t*)(w + 4041984);  // 192000
  uint32_t* bval    = (uint32_t*)(w + 4233984);  // 192000
  uint32_t* bpos    = (uint32_t*)(w + 4425984);  // 192000
  uint32_t* valsB   = (uint32_t*)(w + 4617984);  // 192000
  uint32_t* bcount  = (uint32_t*)(w + 4809984);  // 8192
  uint32_t* bbase   = (uint32_t*)(w + 4818176);  // 8192
  uint32_t* cursor  = (uint32_t*)(w + 4826368);  // 8192

  // zero accumulators (counts+esum contiguous) and first-round bucket counts
  hipMemsetAsync(counts, 0, 8192 + 2097152, stream);
  hipMemsetAsync(bcount, 0, 8192, stream);

  e2_kernel<<<8, 256, 0, stream>>>(embed, e2);
  dist_topk<<<dim3(375, 2), 256, 0, stream>>>(x, embed, e2, pbest, psecond, pbestk);
  merge_halves<<<188, 256, 0, stream>>>(pbest, psecond, pbestk, ind, gap);
  refine<<<48000, 256, 0, stream>>>(x, embed, gap, ind);
  gather_scatter<<<12000, 256, 0, stream>>>(x, embed, ind, outQ, outC, counts, esum);
  ema_stats<<<1, 1024, 0, stream>>>(cs, counts, outNCS, expired, nsum);

  // permutation: round 1 (vals = iota)
  keys_round<<<188, 256, 0, stream>>>(1, keys, valsA, bcount);
  scan2048<<<1, 1024, 0, stream>>>(bcount, bbase, cursor);
  scatter_buckets<<<188, 256, 0, stream>>>(keys, valsA, bbase, cursor, bkey, bval, bpos);
  rank_buckets<<<2048, 64, 0, stream>>>(bkey, bval, bpos, bbase, bcount, valsB);
  // round 2 (vals = round-1 output)
  hipMemsetAsync(bcount, 0, 8192, stream);
  keys_round<<<188, 256, 0, stream>>>(2, keys, nullptr, bcount);
  scan2048<<<1, 1024, 0, stream>>>(bcount, bbase, cursor);
  scatter_buckets<<<188, 256, 0, stream>>>(keys, valsB, bbase, cursor, bkey, bval, bpos);
  rank_buckets<<<2048, 64, 0, stream>>>(bkey, bval, bpos, bbase, bcount, valsA);

  final_embed<<<512, 256, 0, stream>>>(x, cs, counts, eavg, esum, expired, nsum,
                                       valsA, outEAVG, outNE);
}

// Round 2
// 890.141 us; speedup vs baseline: 1.2938x; 1.2938x over previous
//
#include <hip/hip_runtime.h>
#include <hip/hip_bf16.h>
#include <stdint.h>
#include <math.h>

// Problem constants
#define N_TOK 48000     // 32*1500
#define DIMS  256
#define KCB   2048
#define GAP_THR 1e-2f   // bf16x3 dot worst-case score error < 2e-3 -> 5x margin

// JAX threefry flavor: 1 = partitionable (JAX >= 0.4.30 default)
#define JAX_PARTITIONABLE 1

typedef __attribute__((ext_vector_type(8))) short bf16x8;
typedef __attribute__((ext_vector_type(4))) float f32x4;
typedef __attribute__((ext_vector_type(8))) unsigned short u16x8;

// ---------------- bf16 helpers (explicit RNE, independent of HIP lib rounding) ----------------
__device__ __forceinline__ unsigned short bf16rn(float f) {
  uint32_t u = __float_as_uint(f);
  uint32_t r = (u + 0x7FFFu + ((u >> 16) & 1u)) >> 16;
  return (unsigned short)r;
}
__device__ __forceinline__ float bf16f(unsigned short h) {
  return __uint_as_float(((uint32_t)h) << 16);
}

// ---------------- Threefry-2x32 (matches jax._src.prng) ----------------
__device__ inline void tf2x32(uint32_t k0, uint32_t k1, uint32_t c0, uint32_t c1,
                              uint32_t& o0, uint32_t& o1) {
  uint32_t ks2 = k0 ^ k1 ^ 0x1BD11BDAu;
  uint32_t x0 = c0 + k0, x1 = c1 + k1;
#define TF_R(r) { x0 += x1; x1 = (x1 << (r)) | (x1 >> (32 - (r))); x1 ^= x0; }
  TF_R(13) TF_R(15) TF_R(26) TF_R(6)
  x0 += k1; x1 += ks2 + 1u;
  TF_R(17) TF_R(29) TF_R(16) TF_R(24)
  x0 += ks2; x1 += k0 + 2u;
  TF_R(13) TF_R(15) TF_R(26) TF_R(6)
  x0 += k0; x1 += k1 + 3u;
  TF_R(17) TF_R(29) TF_R(16) TF_R(24)
  x0 += k1; x1 += ks2 + 4u;
  TF_R(13) TF_R(15) TF_R(26) TF_R(6)
  x0 += ks2; x1 += k0 + 5u;
#undef TF_R
  o0 = x0; o1 = x1;
}

__device__ inline void get_round_key(int round, uint32_t& ka, uint32_t& kb) {
  const uint32_t b0 = 0u, b1 = 1u;  // jax.random.key(1) -> (0,1)
  uint32_t K1a, K1b, S1a, S1b;
  tf2x32(b0, b1, 0u, 0u, K1a, K1b);
  tf2x32(b0, b1, 0u, 1u, S1a, S1b);
  if (round == 1) { ka = S1a; kb = S1b; return; }
  uint32_t S2a, S2b;
  tf2x32(K1a, K1b, 0u, 1u, S2a, S2b);
  ka = S2a; kb = S2b;
}

__device__ inline uint32_t gen_key(int round, uint32_t i) {
  uint32_t ka, kb, o0, o1;
  get_round_key(round, ka, kb);
  tf2x32(ka, kb, 0u, i, o0, o1);
  return o0 ^ o1;
}

// ---------------- top-2 merge primitive ----------------
__device__ __forceinline__ void mrg(float& b, float& s, int& k,
                                    float ob, float os, int ok) {
  if (ob > b)      { s = fmaxf(b, os); b = ob; k = ok; }
  else if (ob < b) { s = fmaxf(s, ob); }
  else             { s = fmaxf(s, fmaxf(ob, os)); if (ok < k) k = ok; }
}

// ---------------- global_load_lds wrapper (16B) ----------------
__device__ __forceinline__ void gload_lds16(const void* g, void* l) {
  __builtin_amdgcn_global_load_lds(
      (const __attribute__((address_space(1))) uint32_t*)g,
      (__attribute__((address_space(3))) uint32_t*)l, 16, 0, 0);
}

// ---------------- e2[k] = sum(embed[k]^2) ----------------
__global__ void e2_kernel(const float* __restrict__ embed, float* __restrict__ e2) {
  int k = blockIdx.x * blockDim.x + threadIdx.x;
  if (k >= KCB) return;
  const float4* er = (const float4*)(embed + (size_t)k * DIMS);
  float s = 0.f;
  for (int c = 0; c < DIMS / 4; ++c) {
    float4 v = er[c];
    s = fmaf(v.x, v.x, s); s = fmaf(v.y, v.y, s);
    s = fmaf(v.z, v.z, s); s = fmaf(v.w, v.w, s);
  }
  e2[k] = s;
}

// ---------------- split f32 -> bf16 hi + bf16 lo ----------------
__global__ void split_f32(const float* __restrict__ x, unsigned short* __restrict__ hi,
                          unsigned short* __restrict__ lo, int n8) {
  int i = blockIdx.x * blockDim.x + threadIdx.x;
  if (i >= n8) return;
  float4 a = ((const float4*)x)[i * 2];
  float4 b = ((const float4*)x)[i * 2 + 1];
  float v[8] = {a.x, a.y, a.z, a.w, b.x, b.y, b.z, b.w};
  u16x8 h, l;
#pragma unroll
  for (int j = 0; j < 8; ++j) {
    unsigned short hb = bf16rn(v[j]);
    h[j] = hb;
    l[j] = bf16rn(v[j] - bf16f(hb));
  }
  *(u16x8*)&hi[(size_t)i * 8] = h;
  *(u16x8*)&lo[(size_t)i * 8] = l;
}

// ---------------- MFMA distance top-2 ----------------
// score = 2*(xh.eh + xh.el + xl.eh) - e2[k]; 128x128 tile, BK=64, 12 K-steps.
__global__ __launch_bounds__(256, 2) void dist_mfma(
    const unsigned short* __restrict__ xh, const unsigned short* __restrict__ xl,
    const unsigned short* __restrict__ eh, const unsigned short* __restrict__ el,
    const float* __restrict__ e2,
    float* __restrict__ pb, float* __restrict__ ps, int* __restrict__ pk)
{
  __shared__ short As[128 * 64];
  __shared__ short Bs[128 * 64];
  __shared__ float mb[128], msc[128];
  __shared__ int mk[128];

  const int tid = threadIdx.x;
  const int lane = tid & 63, w = tid >> 6;
  const int wr = w >> 1, wc = w & 1;
  const int l15 = lane & 15, lg = lane >> 4;
  const int n0 = blockIdx.x * 128;   // token tile base
  const int c0 = blockIdx.y * 128;   // code tile base

  f32x4 acc[4][4];
#pragma unroll
  for (int mf = 0; mf < 4; ++mf)
#pragma unroll
    for (int nf = 0; nf < 4; ++nf) acc[mf][nf] = (f32x4){0.f, 0.f, 0.f, 0.f};

#pragma unroll 1
  for (int st = 0; st < 12; ++st) {
    const int p = st >> 2;
    const int d0 = (st & 3) << 6;
    const unsigned short* Ag = (p < 2) ? xh : xl;
    const unsigned short* Bg = (p == 1) ? el : eh;
    __syncthreads();
#pragma unroll
    for (int issue = 0; issue < 4; ++issue) {
      const int c = issue * 256 + tid;
      const int row = c >> 3, cc = (c & 7) * 8;
      const int ldsOff = (issue * 256 + w * 64) * 8;  // shorts
      gload_lds16(Ag + (size_t)(n0 + row) * DIMS + d0 + cc, (void*)&As[ldsOff]);
      gload_lds16(Bg + (size_t)(c0 + row) * DIMS + d0 + cc, (void*)&Bs[ldsOff]);
    }
    __syncthreads();
#pragma unroll
    for (int kk = 0; kk < 2; ++kk) {
      const int ko = kk * 32 + lg * 8;
      bf16x8 af[4], bf[4];
#pragma unroll
      for (int mf = 0; mf < 4; ++mf)
        af[mf] = *(const bf16x8*)&As[(wr * 64 + mf * 16 + l15) * 64 + ko];
#pragma unroll
      for (int nf = 0; nf < 4; ++nf)
        bf[nf] = *(const bf16x8*)&Bs[(wc * 64 + nf * 16 + l15) * 64 + ko];
#pragma unroll
      for (int mf = 0; mf < 4; ++mf)
#pragma unroll
        for (int nf = 0; nf < 4; ++nf)
          acc[mf][nf] = __builtin_amdgcn_mfma_f32_16x16x32_bf16(
              af[mf], bf[nf], acc[mf][nf], 0, 0, 0);
    }
  }

  // per-lane columns and e2
  float e2v[4];
#pragma unroll
  for (int nf = 0; nf < 4; ++nf) e2v[nf] = e2[c0 + wc * 64 + nf * 16 + l15];

  float rb[16], rs[16]; int rk[16];
#pragma unroll
  for (int mf = 0; mf < 4; ++mf) {
#pragma unroll
    for (int reg = 0; reg < 4; ++reg) {
      float b = fmaf(2.f, acc[mf][0][reg], -e2v[0]);
      float s = -INFINITY;
      int k = c0 + wc * 64 + l15;
#pragma unroll
      for (int nf = 1; nf < 4; ++nf) {
        float v = fmaf(2.f, acc[mf][nf][reg], -e2v[nf]);
        mrg(b, s, k, v, -INFINITY, c0 + wc * 64 + nf * 16 + l15);
      }
#pragma unroll
      for (int m = 1; m <= 8; m <<= 1) {
        float ob = __shfl_xor(b, m);
        float os = __shfl_xor(s, m);
        int ok = __shfl_xor(k, m);
        mrg(b, s, k, ob, os, ok);
      }
      rb[mf * 4 + reg] = b; rs[mf * 4 + reg] = s; rk[mf * 4 + reg] = k;
    }
  }

  // wc=1 publishes to LDS, wc=0 merges + writes
  if (wc == 1 && l15 == 0) {
#pragma unroll
    for (int mf = 0; mf < 4; ++mf)
#pragma unroll
      for (int reg = 0; reg < 4; ++reg) {
        int r = wr * 64 + mf * 16 + lg * 4 + reg;
        mb[r] = rb[mf * 4 + reg]; msc[r] = rs[mf * 4 + reg]; mk[r] = rk[mf * 4 + reg];
      }
  }
  __syncthreads();
  if (wc == 0 && l15 == 0) {
#pragma unroll
    for (int mf = 0; mf < 4; ++mf)
#pragma unroll
      for (int reg = 0; reg < 4; ++reg) {
        int r = wr * 64 + mf * 16 + lg * 4 + reg;
        float b = rb[mf * 4 + reg], s = rs[mf * 4 + reg];
        int k = rk[mf * 4 + reg];
        mrg(b, s, k, mb[r], msc[r], mk[r]);
        size_t o = (size_t)blockIdx.y * N_TOK + n0 + r;
        pb[o] = b; ps[o] = s; pk[o] = k;
      }
  }
}

// ---------------- merge 16 column-tile partials ----------------
__global__ void merge16(const float* __restrict__ pb, const float* __restrict__ ps,
                        const int* __restrict__ pk,
                        int* __restrict__ ind, float* __restrict__ gap) {
  int n = blockIdx.x * blockDim.x + threadIdx.x;
  if (n >= N_TOK) return;
  float b = pb[n], s = ps[n]; int k = pk[n];
  for (int t = 1; t < 16; ++t) {
    size_t o = (size_t)t * N_TOK + n;
    mrg(b, s, k, pb[o], ps[o], pk[o]);
  }
  ind[n] = k; gap[n] = b - s;
}

// ---------------- f64 re-resolution of near-ties ----------------
__global__ void refine(const float* __restrict__ x, const float* __restrict__ embed,
                       const float* __restrict__ gap, int* __restrict__ ind) {
  const int n = blockIdx.x;
  if (gap[n] >= GAP_THR) return;
  __shared__ double xd[DIMS];
  __shared__ double rv[256];
  __shared__ int    rk[256];
  const int tid = threadIdx.x;
  xd[tid] = (double)x[(size_t)n * DIMS + tid];
  __syncthreads();
  double bb = -1e300; int bk = 0x7fffffff;
  for (int k = tid; k < KCB; k += 256) {
    const float* er = embed + (size_t)k * DIMS;
    double dot = 0.0, ee = 0.0;
    for (int d = 0; d < DIMS; d += 4) {
      float4 e4 = *(const float4*)(er + d);
      dot += xd[d + 0] * (double)e4.x + xd[d + 1] * (double)e4.y
           + xd[d + 2] * (double)e4.z + xd[d + 3] * (double)e4.w;
      ee  += (double)e4.x * e4.x + (double)e4.y * e4.y
           + (double)e4.z * e4.z + (double)e4.w * e4.w;
    }
    double v = 2.0 * dot - ee;
    if (v > bb || (v == bb && k < bk)) { bb = v; bk = k; }
  }
  rv[tid] = bb; rk[tid] = bk;
  __syncthreads();
  for (int s = 128; s > 0; s >>= 1) {
    if (tid < s) {
      double v2 = rv[tid + s]; int k2 = rk[tid + s];
      if (v2 > rv[tid] || (v2 == rv[tid] && k2 < rk[tid])) { rv[tid] = v2; rk[tid] = k2; }
    }
    __syncthreads();
  }
  if (tid == 0) ind[n] = rk[0];
}

// ---------------- quantize gather + codes + counts + embed_sum ----------------
__global__ void gather_scatter(const float* __restrict__ x, const float* __restrict__ embed,
                               const int* __restrict__ ind,
                               float* __restrict__ outq, float* __restrict__ outcodes,
                               float* __restrict__ counts, float* __restrict__ esum) {
  int idx = blockIdx.x * blockDim.x + threadIdx.x;   // over N_TOK*64 float4s
  if (idx >= N_TOK * 64) return;
  int n = idx >> 6, c = idx & 63;
  int k = ind[n];
  float4 e = ((const float4*)embed)[(size_t)k * 64 + c];
  ((float4*)outq)[idx] = e;
  float4 xv = ((const float4*)x)[idx];
  float* base = esum + (size_t)k * DIMS + c * 4;
  atomicAdd(base + 0, xv.x); atomicAdd(base + 1, xv.y);
  atomicAdd(base + 2, xv.z); atomicAdd(base + 3, xv.w);
  if (c == 0) { outcodes[n] = (float)k; atomicAdd(&counts[k], 1.0f); }
}

// ---------------- new_cluster_size + n-sum + expired ----------------
__global__ void ema_stats(const float* __restrict__ cs, const float* __restrict__ counts,
                          float* __restrict__ out_ncs, int* __restrict__ expired,
                          double* __restrict__ nsum) {
  __shared__ double sd[1024];
  int tid = threadIdx.x;
  double local = 0.0;
  for (int k = tid; k < KCB; k += 1024) {
    double v = 0.99 * (double)cs[k] + 0.01 * (double)counts[k];
    out_ncs[k] = (float)v;
    expired[k] = (v < 2.0) ? 1 : 0;
    local += v;
  }
  sd[tid] = local; __syncthreads();
  for (int s = 512; s > 0; s >>= 1) { if (tid < s) sd[tid] += sd[tid + s]; __syncthreads(); }
  if (tid == 0) nsum[0] = sd[0];
}

// ---------------- new_embed_avg + new_embed ----------------
__global__ void final_embed(const float* __restrict__ x, const float* __restrict__ cs,
                            const float* __restrict__ counts,
                            const float* __restrict__ eavg, const float* __restrict__ esum,
                            const int* __restrict__ expired, const double* __restrict__ nsum,
                            const uint32_t* __restrict__ perm,
                            float* __restrict__ out_eavg, float* __restrict__ out_ne) {
  int idx = blockIdx.x * blockDim.x + threadIdx.x;   // over KCB*64 float4s
  if (idx >= KCB * 64) return;
  int k = idx >> 6, c = idx & 63;
  float4 ea = ((const float4*)eavg)[idx];
  float4 es = ((const float4*)esum)[idx];
  double ax = 0.99 * (double)ea.x + 0.01 * (double)es.x;
  double ay = 0.99 * (double)ea.y + 0.01 * (double)es.y;
  double az = 0.99 * (double)ea.z + 0.01 * (double)es.z;
  double aw = 0.99 * (double)ea.w + 0.01 * (double)es.w;
  float4 nv; nv.x = (float)ax; nv.y = (float)ay; nv.z = (float)az; nv.w = (float)aw;
  ((float4*)out_eavg)[idx] = nv;
  float4 r;
  if (expired[k]) {
    r = ((const float4*)x)[(size_t)perm[k] * 64 + c];
  } else {
    double ncs = 0.99 * (double)cs[k] + 0.01 * (double)counts[k];
    double n = nsum[0];
    double sm = (ncs + 1e-5) / (n + 2048.0 * 1e-5) * n;
    r.x = (float)(ax / sm); r.y = (float)(ay / sm);
    r.z = (float)(az / sm); r.w = (float)(aw / sm);
  }
  ((float4*)out_ne)[idx] = r;
}

// ---------------- permutation pipeline (stable sort by random keys) ----------------
__global__ void keys_round(int round, uint32_t* __restrict__ keys,
                           uint32_t* __restrict__ vals_init, uint32_t* __restrict__ bcount) {
  int i = blockIdx.x * blockDim.x + threadIdx.x;
  if (i >= N_TOK) return;
  uint32_t key = gen_key(round, (uint32_t)i);
  keys[i] = key;
  if (vals_init) vals_init[i] = (uint32_t)i;
  atomicAdd(&bcount[key >> 21], 1u);
}

__global__ void scan2048(const uint32_t* __restrict__ in, uint32_t* __restrict__ out,
                         uint32_t* __restrict__ cursor_zero) {
  __shared__ uint32_t buf[2][2048];
  int t = threadIdx.x;   // 1024
  for (int q = 0; q < 2; ++q) buf[0][t + q * 1024] = in[t + q * 1024];
  cursor_zero[t] = 0; cursor_zero[t + 1024] = 0;
  __syncthreads();
  int src = 0;
  for (int off = 1; off < 2048; off <<= 1) {
    for (int q = 0; q < 2; ++q) {
      int i = t + q * 1024;
      uint32_t v = buf[src][i];
      if (i >= off) v += buf[src][i - off];
      buf[src ^ 1][i] = v;
    }
    src ^= 1; __syncthreads();
  }
  for (int q = 0; q < 2; ++q) {
    int i = t + q * 1024;
    out[i] = buf[src][i] - in[i];   // exclusive
  }
}

__global__ void scatter_buckets(const uint32_t* __restrict__ keys, const uint32_t* __restrict__ vals_in,
                                const uint32_t* __restrict__ bbase, uint32_t* __restrict__ cursor,
                                uint32_t* __restrict__ bkey, uint32_t* __restrict__ bval,
                                uint32_t* __restrict__ bpos) {
  int i = blockIdx.x * blockDim.x + threadIdx.x;
  if (i >= N_TOK) return;
  uint32_t k = keys[i];
  uint32_t b = k >> 21;
  uint32_t p = atomicAdd(&cursor[b], 1u);
  uint32_t s = bbase[b] + p;
  bkey[s] = k; bval[s] = vals_in[i]; bpos[s] = (uint32_t)i;
}

__global__ void rank_buckets(const uint32_t* __restrict__ bkey, const uint32_t* __restrict__ bval,
                             const uint32_t* __restrict__ bpos, const uint32_t* __restrict__ bbase,
                             const uint32_t* __restrict__ bcount, uint32_t* __restrict__ out_vals) {
  int b = blockIdx.x;
  uint32_t base = bbase[b], cnt = bcount[b];
  for (uint32_t t = threadIdx.x; t < cnt; t += blockDim.x) {
    uint32_t k = bkey[base + t], p = bpos[base + t];
    uint32_t r = 0;
    for (uint32_t j = 0; j < cnt; ++j) {
      uint32_t kj = bkey[base + j], pj = bpos[base + j];
      r += (kj < k) | ((kj == k) & (pj < p));
    }
    out_vals[base + r] = bval[base + t];
  }
}

// ---------------- launch ----------------
extern "C" void kernel_launch(void* const* d_in, const int* in_sizes, int n_in,
                              void* d_out, int out_size, void* d_ws, size_t ws_size,
                              hipStream_t stream) {
  const float* x     = (const float*)d_in[0];
  const float* embed = (const float*)d_in[1];
  const float* cs    = (const float*)d_in[2];
  const float* eavg  = (const float*)d_in[3];

  float* out = (float*)d_out;
  float* outQ    = out;                  // 12,288,000
  float* outC    = out + 12288000;       // 48,000
  float* outNCS  = out + 12336000;       // 2,048
  float* outEAVG = out + 12338048;       // 524,288
  float* outNE   = out + 12862336;       // 524,288

  char* w = (char*)d_ws;
  size_t off = 0;
  auto alloc = [&](size_t bytes) -> void* {
    void* p = w + off; off += (bytes + 255) & ~(size_t)255; return p;
  };
  unsigned short* xh = (unsigned short*)alloc((size_t)N_TOK * DIMS * 2);
  unsigned short* xl = (unsigned short*)alloc((size_t)N_TOK * DIMS * 2);
  unsigned short* eh = (unsigned short*)alloc((size_t)KCB * DIMS * 2);
  unsigned short* el = (unsigned short*)alloc((size_t)KCB * DIMS * 2);
  float*    e2      = (float*)alloc(KCB * 4);
  float*    counts  = (float*)alloc(KCB * 4);
  float*    esum    = (float*)alloc((size_t)KCB * DIMS * 4);   // contiguous after counts
  float*    pbest   = (float*)alloc((size_t)16 * N_TOK * 4);
  float*    psecond = (float*)alloc((size_t)16 * N_TOK * 4);
  int*      pbestk  = (int*)alloc((size_t)16 * N_TOK * 4);
  int*      ind     = (int*)alloc(N_TOK * 4);
  float*    gap     = (float*)alloc(N_TOK * 4);
  double*   nsum    = (double*)alloc(256);
  int*      expired = (int*)alloc(KCB * 4);
  uint32_t* keys    = (uint32_t*)alloc(N_TOK * 4);
  uint32_t* valsA   = (uint32_t*)alloc(N_TOK * 4);
  uint32_t* bkey    = (uint32_t*)alloc(N_TOK * 4);
  uint32_t* bval    = (uint32_t*)alloc(N_TOK * 4);
  uint32_t* bpos    = (uint32_t*)alloc(N_TOK * 4);
  uint32_t* valsB   = (uint32_t*)alloc(N_TOK * 4);
  uint32_t* bcount  = (uint32_t*)alloc(KCB * 4);
  uint32_t* bbase   = (uint32_t*)alloc(KCB * 4);
  uint32_t* cursor  = (uint32_t*)alloc(KCB * 4);

  // zero accumulators (counts+esum contiguous) and first-round bucket counts
  hipMemsetAsync(counts, 0, KCB * 4 + (size_t)KCB * DIMS * 4, stream);
  hipMemsetAsync(bcount, 0, KCB * 4, stream);

  e2_kernel<<<8, 256, 0, stream>>>(embed, e2);
  split_f32<<<6000, 256, 0, stream>>>(x, xh, xl, N_TOK * DIMS / 8);
  split_f32<<<256, 256, 0, stream>>>(embed, eh, el, KCB * DIMS / 8);

  dist_mfma<<<dim3(375, 16), 256, 0, stream>>>(xh, xl, eh, el, e2,
                                               pbest, psecond, pbestk);
  merge16<<<188, 256, 0, stream>>>(pbest, psecond, pbestk, ind, gap);
  refine<<<48000, 256, 0, stream>>>(x, embed, gap, ind);
  gather_scatter<<<12000, 256, 0, stream>>>(x, embed, ind, outQ, outC, counts, esum);
  ema_stats<<<1, 1024, 0, stream>>>(cs, counts, outNCS, expired, nsum);

  // permutation: round 1 (vals = iota)
  keys_round<<<188, 256, 0, stream>>>(1, keys, valsA, bcount);
  scan2048<<<1, 1024, 0, stream>>>(bcount, bbase, cursor);
  scatter_buckets<<<188, 256, 0, stream>>>(keys, valsA, bbase, cursor, bkey, bval, bpos);
  rank_buckets<<<2048, 64, 0, stream>>>(bkey, bval, bpos, bbase, bcount, valsB);
  // round 2 (vals = round-1 output)
  hipMemsetAsync(bcount, 0, KCB * 4, stream);
  keys_round<<<188, 256, 0, stream>>>(2, keys, nullptr, bcount);
  scan2048<<<1, 1024, 0, stream>>>(bcount, bbase, cursor);
  scatter_buckets<<<188, 256, 0, stream>>>(keys, valsB, bbase, cursor, bkey, bval, bpos);
  rank_buckets<<<2048, 64, 0, stream>>>(bkey, bval, bpos, bbase, bcount, valsA);

  final_embed<<<512, 256, 0, stream>>>(x, cs, counts, eavg, esum, expired, nsum,
                                       valsA, outEAVG, outNE);
}

// Round 3
// 623.189 us; speedup vs baseline: 1.8480x; 1.4284x over previous
//
#include <hip/hip_runtime.h>
#include <hip/hip_bf16.h>
#include <stdint.h>
#include <math.h>

// Problem constants
#define N_TOK 48000     // 32*1500
#define DIMS  256
#define KCB   2048
#define GAP_THR 4e-3f   // >= 2x worst-case bf16x3+MFMA score error (~6e-4), 6x margin

typedef __attribute__((ext_vector_type(8))) short bf16x8;
typedef __attribute__((ext_vector_type(4))) float f32x4;
typedef __attribute__((ext_vector_type(8))) unsigned short u16x8;

// ---------------- bf16 helpers (explicit RNE) ----------------
__device__ __forceinline__ unsigned short bf16rn(float f) {
  uint32_t u = __float_as_uint(f);
  uint32_t r = (u + 0x7FFFu + ((u >> 16) & 1u)) >> 16;
  return (unsigned short)r;
}
__device__ __forceinline__ float bf16f(unsigned short h) {
  return __uint_as_float(((uint32_t)h) << 16);
}

// ---------------- Threefry-2x32 (matches jax._src.prng, partitionable) ----------------
__device__ inline void tf2x32(uint32_t k0, uint32_t k1, uint32_t c0, uint32_t c1,
                              uint32_t& o0, uint32_t& o1) {
  uint32_t ks2 = k0 ^ k1 ^ 0x1BD11BDAu;
  uint32_t x0 = c0 + k0, x1 = c1 + k1;
#define TF_R(r) { x0 += x1; x1 = (x1 << (r)) | (x1 >> (32 - (r))); x1 ^= x0; }
  TF_R(13) TF_R(15) TF_R(26) TF_R(6)
  x0 += k1; x1 += ks2 + 1u;
  TF_R(17) TF_R(29) TF_R(16) TF_R(24)
  x0 += ks2; x1 += k0 + 2u;
  TF_R(13) TF_R(15) TF_R(26) TF_R(6)
  x0 += k0; x1 += k1 + 3u;
  TF_R(17) TF_R(29) TF_R(16) TF_R(24)
  x0 += k1; x1 += ks2 + 4u;
  TF_R(13) TF_R(15) TF_R(26) TF_R(6)
  x0 += ks2; x1 += k0 + 5u;
#undef TF_R
  o0 = x0; o1 = x1;
}

__device__ inline void get_round_key(int round, uint32_t& ka, uint32_t& kb) {
  const uint32_t b0 = 0u, b1 = 1u;  // jax.random.key(1) -> (0,1)
  uint32_t K1a, K1b, S1a, S1b;
  tf2x32(b0, b1, 0u, 0u, K1a, K1b);
  tf2x32(b0, b1, 0u, 1u, S1a, S1b);
  if (round == 1) { ka = S1a; kb = S1b; return; }
  uint32_t S2a, S2b;
  tf2x32(K1a, K1b, 0u, 1u, S2a, S2b);
  ka = S2a; kb = S2b;
}

__device__ inline uint32_t gen_key(int round, uint32_t i) {
  uint32_t ka, kb, o0, o1;
  get_round_key(round, ka, kb);
  tf2x32(ka, kb, 0u, i, o0, o1);
  return o0 ^ o1;
}

// ---------------- top-3 (values) + top-2 (indices) primitives ----------------
__device__ __forceinline__ bool gtr(float v1, int k1, float v2, int k2) {
  return (v1 > v2) || (v1 == v2 && k1 < k2);
}
__device__ __forceinline__ void ins3(float& b, float& s, float& t, int& kb, int& ks,
                                     float v, int k) {
  if (gtr(v, k, b, kb))      { t = s; s = b; ks = kb; b = v; kb = k; }
  else if (gtr(v, k, s, ks)) { t = s; s = v; ks = k; }
  else t = fmaxf(t, v);
}
// merge two top-3 sets (disjoint code sets)
__device__ __forceinline__ void mrg3(float& b, float& s, float& t, int& kb, int& ks,
                                     float ob, float os, float ot, int okb, int oks) {
  float nb, ns, m2; int nkb, nks;
  if (gtr(b, kb, ob, okb)) {
    nb = b; nkb = kb;
    if (gtr(s, ks, ob, okb)) { ns = s; nks = ks; m2 = ob; }
    else { ns = ob; nks = okb; m2 = fmaxf(s, os); }
  } else {
    nb = ob; nkb = okb;
    if (gtr(os, oks, b, kb)) { ns = os; nks = oks; m2 = b; }
    else { ns = b; nks = kb; m2 = fmaxf(os, s); }
  }
  t = fmaxf(m2, fmaxf(t, ot));
  b = nb; s = ns; kb = nkb; ks = nks;
}

// ---------------- global_load_lds wrapper (16B) ----------------
__device__ __forceinline__ void gload_lds16(const void* g, void* l) {
  __builtin_amdgcn_global_load_lds(
      (const __attribute__((address_space(1))) uint32_t*)g,
      (__attribute__((address_space(3))) uint32_t*)l, 16, 0, 0);
}

// ---------------- e2[k] = sum(embed[k]^2) ----------------
__global__ void e2_kernel(const float* __restrict__ embed, float* __restrict__ e2) {
  int k = blockIdx.x * blockDim.x + threadIdx.x;
  if (k >= KCB) return;
  const float4* er = (const float4*)(embed + (size_t)k * DIMS);
  float s = 0.f;
  for (int c = 0; c < DIMS / 4; ++c) {
    float4 v = er[c];
    s = fmaf(v.x, v.x, s); s = fmaf(v.y, v.y, s);
    s = fmaf(v.z, v.z, s); s = fmaf(v.w, v.w, s);
  }
  e2[k] = s;
}

// ---------------- split f32 -> bf16 hi + bf16 lo ----------------
__global__ void split_f32(const float* __restrict__ x, unsigned short* __restrict__ hi,
                          unsigned short* __restrict__ lo, int n8) {
  int i = blockIdx.x * blockDim.x + threadIdx.x;
  if (i >= n8) return;
  float4 a = ((const float4*)x)[i * 2];
  float4 b = ((const float4*)x)[i * 2 + 1];
  float v[8] = {a.x, a.y, a.z, a.w, b.x, b.y, b.z, b.w};
  u16x8 h, l;
#pragma unroll
  for (int j = 0; j < 8; ++j) {
    unsigned short hb = bf16rn(v[j]);
    h[j] = hb;
    l[j] = bf16rn(v[j] - bf16f(hb));
  }
  *(u16x8*)&hi[(size_t)i * 8] = h;
  *(u16x8*)&lo[(size_t)i * 8] = l;
}

// ---------------- MFMA distance top-3 ----------------
// score = 2*(xh.eh + xh.el + xl.eh) - e2[k]; 128x128 tile, BK=64, 12 K-steps.
__global__ __launch_bounds__(256, 2) void dist_mfma(
    const unsigned short* __restrict__ xh, const unsigned short* __restrict__ xl,
    const unsigned short* __restrict__ eh, const unsigned short* __restrict__ el,
    const float* __restrict__ e2,
    float* __restrict__ pb, float* __restrict__ ps, float* __restrict__ pt,
    uint32_t* __restrict__ pkk)
{
  __shared__ short As[128 * 64];
  __shared__ short Bs[128 * 64];
  __shared__ float mbv[128], msv[128], mtv[128];
  __shared__ int mkb[128], mks[128];

  const int tid = threadIdx.x;
  const int lane = tid & 63, w = tid >> 6;
  const int wr = w >> 1, wc = w & 1;
  const int l15 = lane & 15, lg = lane >> 4;
  const int n0 = blockIdx.x * 128;   // token tile base
  const int c0 = blockIdx.y * 128;   // code tile base

  f32x4 acc[4][4];
#pragma unroll
  for (int mf = 0; mf < 4; ++mf)
#pragma unroll
    for (int nf = 0; nf < 4; ++nf) acc[mf][nf] = (f32x4){0.f, 0.f, 0.f, 0.f};

#pragma unroll 1
  for (int st = 0; st < 12; ++st) {
    const int p = st >> 2;
    const int d0 = (st & 3) << 6;
    const unsigned short* Ag = (p < 2) ? xh : xl;
    const unsigned short* Bg = (p == 1) ? el : eh;
    __syncthreads();
#pragma unroll
    for (int issue = 0; issue < 4; ++issue) {
      const int c = issue * 256 + tid;
      const int row = c >> 3, cc = (c & 7) * 8;
      const int ldsOff = (issue * 256 + w * 64) * 8;  // shorts
      gload_lds16(Ag + (size_t)(n0 + row) * DIMS + d0 + cc, (void*)&As[ldsOff]);
      gload_lds16(Bg + (size_t)(c0 + row) * DIMS + d0 + cc, (void*)&Bs[ldsOff]);
    }
    __syncthreads();
#pragma unroll
    for (int kk = 0; kk < 2; ++kk) {
      const int ko = kk * 32 + lg * 8;
      bf16x8 af[4], bf[4];
#pragma unroll
      for (int mf = 0; mf < 4; ++mf)
        af[mf] = *(const bf16x8*)&As[(wr * 64 + mf * 16 + l15) * 64 + ko];
#pragma unroll
      for (int nf = 0; nf < 4; ++nf)
        bf[nf] = *(const bf16x8*)&Bs[(wc * 64 + nf * 16 + l15) * 64 + ko];
#pragma unroll
      for (int mf = 0; mf < 4; ++mf)
#pragma unroll
        for (int nf = 0; nf < 4; ++nf)
          acc[mf][nf] = __builtin_amdgcn_mfma_f32_16x16x32_bf16(
              af[mf], bf[nf], acc[mf][nf], 0, 0, 0);
    }
  }

  float e2v[4];
#pragma unroll
  for (int nf = 0; nf < 4; ++nf) e2v[nf] = e2[c0 + wc * 64 + nf * 16 + l15];

  float rb[16], rs[16], rt[16]; int rkb[16], rks[16];
#pragma unroll
  for (int mf = 0; mf < 4; ++mf) {
#pragma unroll
    for (int reg = 0; reg < 4; ++reg) {
      float b = fmaf(2.f, acc[mf][0][reg], -e2v[0]);
      float s = -INFINITY, t = -INFINITY;
      int kb = c0 + wc * 64 + l15, ks = 0x7fffffff;
#pragma unroll
      for (int nf = 1; nf < 4; ++nf) {
        float v = fmaf(2.f, acc[mf][nf][reg], -e2v[nf]);
        ins3(b, s, t, kb, ks, v, c0 + wc * 64 + nf * 16 + l15);
      }
#pragma unroll
      for (int m = 1; m <= 8; m <<= 1) {
        float ob = __shfl_xor(b, m), os = __shfl_xor(s, m), ot = __shfl_xor(t, m);
        int okb = __shfl_xor(kb, m), oks = __shfl_xor(ks, m);
        mrg3(b, s, t, kb, ks, ob, os, ot, okb, oks);
      }
      int q = mf * 4 + reg;
      rb[q] = b; rs[q] = s; rt[q] = t; rkb[q] = kb; rks[q] = ks;
    }
  }

  // wc=1 publishes to LDS, wc=0 merges + writes
  if (wc == 1 && l15 == 0) {
#pragma unroll
    for (int mf = 0; mf < 4; ++mf)
#pragma unroll
      for (int reg = 0; reg < 4; ++reg) {
        int q = mf * 4 + reg;
        int r = wr * 64 + mf * 16 + lg * 4 + reg;
        mbv[r] = rb[q]; msv[r] = rs[q]; mtv[r] = rt[q];
        mkb[r] = rkb[q]; mks[r] = rks[q];
      }
  }
  __syncthreads();
  if (wc == 0 && l15 == 0) {
#pragma unroll
    for (int mf = 0; mf < 4; ++mf)
#pragma unroll
      for (int reg = 0; reg < 4; ++reg) {
        int q = mf * 4 + reg;
        int r = wr * 64 + mf * 16 + lg * 4 + reg;
        float b = rb[q], s = rs[q], t = rt[q];
        int kb = rkb[q], ks = rks[q];
        mrg3(b, s, t, kb, ks, mbv[r], msv[r], mtv[r], mkb[r], mks[r]);
        size_t o = (size_t)blockIdx.y * N_TOK + n0 + r;
        pb[o] = b; ps[o] = s; pt[o] = t;
        pkk[o] = ((uint32_t)kb << 16) | (uint32_t)ks;
      }
  }
}

// ---------------- merge 16 column-tile partials + classify ----------------
__global__ void merge16(const float* __restrict__ pb, const float* __restrict__ ps,
                        const float* __restrict__ pt, const uint32_t* __restrict__ pkk,
                        int* __restrict__ ind, int4* __restrict__ pairs,
                        int* __restrict__ listB,
                        uint32_t* __restrict__ cntA, uint32_t* __restrict__ cntB) {
  int n = blockIdx.x * blockDim.x + threadIdx.x;
  if (n >= N_TOK) return;
  float b = pb[n], s = ps[n], t = pt[n];
  uint32_t kk = pkk[n];
  int kb = (int)(kk >> 16), ks = (int)(kk & 0xffffu);
  for (int tt = 1; tt < 16; ++tt) {
    size_t o = (size_t)tt * N_TOK + n;
    uint32_t k2 = pkk[o];
    mrg3(b, s, t, kb, ks, pb[o], ps[o], pt[o], (int)(k2 >> 16), (int)(k2 & 0xffffu));
  }
  ind[n] = kb;
  if (b - s < GAP_THR) {
    if (b - t >= GAP_THR) {
      uint32_t i = atomicAdd(cntA, 1u);
      pairs[i] = make_int4(n, kb, ks, 0);
    } else {
      uint32_t i = atomicAdd(cntB, 1u);
      listB[i] = n;
    }
  }
}

// ---------------- wave-per-row f64 pair decider ----------------
__global__ void refine_pair(const float* __restrict__ x, const float* __restrict__ embed,
                            const int4* __restrict__ pairs, const uint32_t* __restrict__ cntA,
                            int* __restrict__ ind) {
  const uint32_t nA = cntA[0];
  const int lane = threadIdx.x & 63;
  const uint32_t wid = (blockIdx.x * blockDim.x + threadIdx.x) >> 6;
  const uint32_t nw = (gridDim.x * blockDim.x) >> 6;
  for (uint32_t i = wid; i < nA; i += nw) {
    int4 p = pairs[i];
    const int n = p.x, k1 = p.y, k2 = p.z;
    float4 xv = ((const float4*)x)[(size_t)n * 64 + lane];
    float4 a  = ((const float4*)embed)[(size_t)k1 * 64 + lane];
    float4 c  = ((const float4*)embed)[(size_t)k2 * 64 + lane];
    double s1 = 2.0 * ((double)xv.x * a.x + (double)xv.y * a.y
                     + (double)xv.z * a.z + (double)xv.w * a.w)
              - ((double)a.x * a.x + (double)a.y * a.y
               + (double)a.z * a.z + (double)a.w * a.w);
    double s2 = 2.0 * ((double)xv.x * c.x + (double)xv.y * c.y
                     + (double)xv.z * c.z + (double)xv.w * c.w)
              - ((double)c.x * c.x + (double)c.y * c.y
               + (double)c.z * c.z + (double)c.w * c.w);
#pragma unroll
    for (int m = 1; m < 64; m <<= 1) {
      s1 += __shfl_xor(s1, m);
      s2 += __shfl_xor(s2, m);
    }
    if (lane == 0) {
      int wk = (s1 > s2) ? k1 : ((s2 > s1) ? k2 : min(k1, k2));
      ind[n] = wk;
    }
  }
}

// ---------------- full f64 re-scan fallback (rare) ----------------
__global__ void refine_full(const float* __restrict__ x, const float* __restrict__ embed,
                            const int* __restrict__ listB, const uint32_t* __restrict__ cntB,
                            int* __restrict__ ind) {
  __shared__ double xd[DIMS];
  __shared__ double rv[256];
  __shared__ int    rk[256];
  const int tid = threadIdx.x;
  const uint32_t nB = cntB[0];
  for (uint32_t it = blockIdx.x; it < nB; it += gridDim.x) {
    const int n = listB[it];
    __syncthreads();
    xd[tid] = (double)x[(size_t)n * DIMS + tid];
    __syncthreads();
    double bb = -1e300; int bk = 0x7fffffff;
    for (int k = tid; k < KCB; k += 256) {
      const float* er = embed + (size_t)k * DIMS;
      double dot = 0.0, ee = 0.0;
      for (int d = 0; d < DIMS; d += 4) {
        float4 e4 = *(const float4*)(er + d);
        dot += xd[d + 0] * (double)e4.x + xd[d + 1] * (double)e4.y
             + xd[d + 2] * (double)e4.z + xd[d + 3] * (double)e4.w;
        ee  += (double)e4.x * e4.x + (double)e4.y * e4.y
             + (double)e4.z * e4.z + (double)e4.w * e4.w;
      }
      double v = 2.0 * dot - ee;
      if (v > bb || (v == bb && k < bk)) { bb = v; bk = k; }
    }
    rv[tid] = bb; rk[tid] = bk;
    __syncthreads();
    for (int s = 128; s > 0; s >>= 1) {
      if (tid < s) {
        double v2 = rv[tid + s]; int k2 = rk[tid + s];
        if (v2 > rv[tid] || (v2 == rv[tid] && k2 < rk[tid])) { rv[tid] = v2; rk[tid] = k2; }
      }
      __syncthreads();
    }
    if (tid == 0) ind[n] = rk[0];
  }
}

// ---------------- quantize gather + codes + counts + embed_sum ----------------
__global__ void gather_scatter(const float* __restrict__ x, const float* __restrict__ embed,
                               const int* __restrict__ ind,
                               float* __restrict__ outq, float* __restrict__ outcodes,
                               float* __restrict__ counts, float* __restrict__ esum) {
  int idx = blockIdx.x * blockDim.x + threadIdx.x;   // over N_TOK*64 float4s
  if (idx >= N_TOK * 64) return;
  int n = idx >> 6, c = idx & 63;
  int k = ind[n];
  float4 e = ((const float4*)embed)[(size_t)k * 64 + c];
  ((float4*)outq)[idx] = e;
  float4 xv = ((const float4*)x)[idx];
  float* base = esum + (size_t)k * DIMS + c * 4;
  atomicAdd(base + 0, xv.x); atomicAdd(base + 1, xv.y);
  atomicAdd(base + 2, xv.z); atomicAdd(base + 3, xv.w);
  if (c == 0) { outcodes[n] = (float)k; atomicAdd(&counts[k], 1.0f); }
}

// ---------------- new_cluster_size + n-sum + expired ----------------
__global__ void ema_stats(const float* __restrict__ cs, const float* __restrict__ counts,
                          float* __restrict__ out_ncs, int* __restrict__ expired,
                          double* __restrict__ nsum) {
  __shared__ double sd[1024];
  int tid = threadIdx.x;
  double local = 0.0;
  for (int k = tid; k < KCB; k += 1024) {
    double v = 0.99 * (double)cs[k] + 0.01 * (double)counts[k];
    out_ncs[k] = (float)v;
    expired[k] = (v < 2.0) ? 1 : 0;
    local += v;
  }
  sd[tid] = local; __syncthreads();
  for (int s = 512; s > 0; s >>= 1) { if (tid < s) sd[tid] += sd[tid + s]; __syncthreads(); }
  if (tid == 0) nsum[0] = sd[0];
}

// ---------------- new_embed_avg + new_embed ----------------
__global__ void final_embed(const float* __restrict__ x, const float* __restrict__ cs,
                            const float* __restrict__ counts,
                            const float* __restrict__ eavg, const float* __restrict__ esum,
                            const int* __restrict__ expired, const double* __restrict__ nsum,
                            const uint32_t* __restrict__ perm,
                            float* __restrict__ out_eavg, float* __restrict__ out_ne) {
  int idx = blockIdx.x * blockDim.x + threadIdx.x;   // over KCB*64 float4s
  if (idx >= KCB * 64) return;
  int k = idx >> 6, c = idx & 63;
  float4 ea = ((const float4*)eavg)[idx];
  float4 es = ((const float4*)esum)[idx];
  double ax = 0.99 * (double)ea.x + 0.01 * (double)es.x;
  double ay = 0.99 * (double)ea.y + 0.01 * (double)es.y;
  double az = 0.99 * (double)ea.z + 0.01 * (double)es.z;
  double aw = 0.99 * (double)ea.w + 0.01 * (double)es.w;
  float4 nv; nv.x = (float)ax; nv.y = (float)ay; nv.z = (float)az; nv.w = (float)aw;
  ((float4*)out_eavg)[idx] = nv;
  float4 r;
  if (expired[k]) {
    r = ((const float4*)x)[(size_t)perm[k] * 64 + c];
  } else {
    double ncs = 0.99 * (double)cs[k] + 0.01 * (double)counts[k];
    double n = nsum[0];
    double sm = (ncs + 1e-5) / (n + 2048.0 * 1e-5) * n;
    r.x = (float)(ax / sm); r.y = (float)(ay / sm);
    r.z = (float)(az / sm); r.w = (float)(aw / sm);
  }
  ((float4*)out_ne)[idx] = r;
}

// ---------------- permutation pipeline (stable sort by random keys) ----------------
__global__ void keys_round(int round, uint32_t* __restrict__ keys,
                           uint32_t* __restrict__ vals_init, uint32_t* __restrict__ bcount) {
  int i = blockIdx.x * blockDim.x + threadIdx.x;
  if (i >= N_TOK) return;
  uint32_t key = gen_key(round, (uint32_t)i);
  keys[i] = key;
  if (vals_init) vals_init[i] = (uint32_t)i;
  atomicAdd(&bcount[key >> 21], 1u);
}

__global__ void scan2048(const uint32_t* __restrict__ in, uint32_t* __restrict__ out,
                         uint32_t* __restrict__ cursor_zero) {
  __shared__ uint32_t buf[2][2048];
  int t = threadIdx.x;   // 1024
  for (int q = 0; q < 2; ++q) buf[0][t + q * 1024] = in[t + q * 1024];
  cursor_zero[t] = 0; cursor_zero[t + 1024] = 0;
  __syncthreads();
  int src = 0;
  for (int off = 1; off < 2048; off <<= 1) {
    for (int q = 0; q < 2; ++q) {
      int i = t + q * 1024;
      uint32_t v = buf[src][i];
      if (i >= off) v += buf[src][i - off];
      buf[src ^ 1][i] = v;
    }
    src ^= 1; __syncthreads();
  }
  for (int q = 0; q < 2; ++q) {
    int i = t + q * 1024;
    out[i] = buf[src][i] - in[i];   // exclusive
  }
}

__global__ void scatter_buckets(const uint32_t* __restrict__ keys, const uint32_t* __restrict__ vals_in,
                                const uint32_t* __restrict__ bbase, uint32_t* __restrict__ cursor,
                                uint32_t* __restrict__ bkey, uint32_t* __restrict__ bval,
                                uint32_t* __restrict__ bpos) {
  int i = blockIdx.x * blockDim.x + threadIdx.x;
  if (i >= N_TOK) return;
  uint32_t k = keys[i];
  uint32_t b = k >> 21;
  uint32_t p = atomicAdd(&cursor[b], 1u);
  uint32_t s = bbase[b] + p;
  bkey[s] = k; bval[s] = vals_in[i]; bpos[s] = (uint32_t)i;
}

__global__ void rank_buckets(const uint32_t* __restrict__ bkey, const uint32_t* __restrict__ bval,
                             const uint32_t* __restrict__ bpos, const uint32_t* __restrict__ bbase,
                             const uint32_t* __restrict__ bcount, uint32_t* __restrict__ out_vals) {
  int b = blockIdx.x;
  uint32_t base = bbase[b], cnt = bcount[b];
  for (uint32_t t = threadIdx.x; t < cnt; t += blockDim.x) {
    uint32_t k = bkey[base + t], p = bpos[base + t];
    uint32_t r = 0;
    for (uint32_t j = 0; j < cnt; ++j) {
      uint32_t kj = bkey[base + j], pj = bpos[base + j];
      r += (kj < k) | ((kj == k) & (pj < p));
    }
    out_vals[base + r] = bval[base + t];
  }
}

// ---------------- launch ----------------
extern "C" void kernel_launch(void* const* d_in, const int* in_sizes, int n_in,
                              void* d_out, int out_size, void* d_ws, size_t ws_size,
                              hipStream_t stream) {
  const float* x     = (const float*)d_in[0];
  const float* embed = (const float*)d_in[1];
  const float* cs    = (const float*)d_in[2];
  const float* eavg  = (const float*)d_in[3];

  float* out = (float*)d_out;
  float* outQ    = out;                  // 12,288,000
  float* outC    = out + 12288000;       // 48,000
  float* outNCS  = out + 12336000;       // 2,048
  float* outEAVG = out + 12338048;       // 524,288
  float* outNE   = out + 12862336;       // 524,288

  char* w = (char*)d_ws;
  size_t off = 0;
  auto alloc = [&](size_t bytes) -> void* {
    void* p = w + off; off += (bytes + 255) & ~(size_t)255; return p;
  };
  unsigned short* xh = (unsigned short*)alloc((size_t)N_TOK * DIMS * 2);
  unsigned short* xl = (unsigned short*)alloc((size_t)N_TOK * DIMS * 2);
  unsigned short* eh = (unsigned short*)alloc((size_t)KCB * DIMS * 2);
  unsigned short* el = (unsigned short*)alloc((size_t)KCB * DIMS * 2);
  float*    e2      = (float*)alloc(KCB * 4);
  float*    counts  = (float*)alloc(KCB * 4);
  float*    esum    = (float*)alloc((size_t)KCB * DIMS * 4);   // contiguous after counts
  float*    pbest   = (float*)alloc((size_t)16 * N_TOK * 4);
  float*    psecond = (float*)alloc((size_t)16 * N_TOK * 4);
  float*    pthird  = (float*)alloc((size_t)16 * N_TOK * 4);
  uint32_t* pkk     = (uint32_t*)alloc((size_t)16 * N_TOK * 4);
  int*      ind     = (int*)alloc(N_TOK * 4);
  int4*     pairs   = (int4*)alloc((size_t)N_TOK * 16);
  int*      listB   = (int*)alloc(N_TOK * 4);
  uint32_t* cntAB   = (uint32_t*)alloc(256);      // [0]=cntA, [1]=cntB
  double*   nsum    = (double*)alloc(256);
  int*      expired = (int*)alloc(KCB * 4);
  uint32_t* keys    = (uint32_t*)alloc(N_TOK * 4);
  uint32_t* valsA   = (uint32_t*)alloc(N_TOK * 4);
  uint32_t* bkey    = (uint32_t*)alloc(N_TOK * 4);
  uint32_t* bval    = (uint32_t*)alloc(N_TOK * 4);
  uint32_t* bpos    = (uint32_t*)alloc(N_TOK * 4);
  uint32_t* valsB   = (uint32_t*)alloc(N_TOK * 4);
  uint32_t* bcount  = (uint32_t*)alloc(KCB * 4);
  uint32_t* bbase   = (uint32_t*)alloc(KCB * 4);
  uint32_t* cursor  = (uint32_t*)alloc(KCB * 4);

  // zero accumulators (counts+esum contiguous), tie counters, bucket counts
  hipMemsetAsync(counts, 0, KCB * 4 + (size_t)KCB * DIMS * 4, stream);
  hipMemsetAsync(cntAB, 0, 256, stream);
  hipMemsetAsync(bcount, 0, KCB * 4, stream);

  e2_kernel<<<8, 256, 0, stream>>>(embed, e2);
  split_f32<<<6000, 256, 0, stream>>>(x, xh, xl, N_TOK * DIMS / 8);
  split_f32<<<256, 256, 0, stream>>>(embed, eh, el, KCB * DIMS / 8);

  dist_mfma<<<dim3(375, 16), 256, 0, stream>>>(xh, xl, eh, el, e2,
                                               pbest, psecond, pthird, pkk);
  merge16<<<188, 256, 0, stream>>>(pbest, psecond, pthird, pkk,
                                   ind, pairs, listB, &cntAB[0], &cntAB[1]);
  refine_pair<<<128, 256, 0, stream>>>(x, embed, pairs, &cntAB[0], ind);
  refine_full<<<64, 256, 0, stream>>>(x, embed, listB, &cntAB[1], ind);

  gather_scatter<<<12000, 256, 0, stream>>>(x, embed, ind, outQ, outC, counts, esum);
  ema_stats<<<1, 1024, 0, stream>>>(cs, counts, outNCS, expired, nsum);

  // permutation: round 1 (vals = iota)
  keys_round<<<188, 256, 0, stream>>>(1, keys, valsA, bcount);
  scan2048<<<1, 1024, 0, stream>>>(bcount, bbase, cursor);
  scatter_buckets<<<188, 256, 0, stream>>>(keys, valsA, bbase, cursor, bkey, bval, bpos);
  rank_buckets<<<2048, 64, 0, stream>>>(bkey, bval, bpos, bbase, bcount, valsB);
  // round 2 (vals = round-1 output)
  hipMemsetAsync(bcount, 0, KCB * 4, stream);
  keys_round<<<188, 256, 0, stream>>>(2, keys, nullptr, bcount);
  scan2048<<<1, 1024, 0, stream>>>(bcount, bbase, cursor);
  scatter_buckets<<<188, 256, 0, stream>>>(keys, valsB, bbase, cursor, bkey, bval, bpos);
  rank_buckets<<<2048, 64, 0, stream>>>(bkey, bval, bpos, bbase, bcount, valsA);

  final_embed<<<512, 256, 0, stream>>>(x, cs, counts, eavg, esum, expired, nsum,
                                       valsA, outEAVG, outNE);
}

// Round 4
// 539.261 us; speedup vs baseline: 2.1356x; 1.1556x over previous
//
#include <hip/hip_runtime.h>
#include <hip/hip_bf16.h>
#include <stdint.h>
#include <math.h>

// Problem constants
#define N_TOK 48000     // 32*1500
#define DIMS  256
#define KCB   2048
#define GAP_THR 4e-3f   // >= 2x worst-case bf16x3+MFMA score error (~6e-4), 6x margin

typedef __attribute__((ext_vector_type(8))) short bf16x8;
typedef __attribute__((ext_vector_type(4))) float f32x4;
typedef __attribute__((ext_vector_type(8))) unsigned short u16x8;

// ---------------- bf16 helpers (explicit RNE) ----------------
__device__ __forceinline__ unsigned short bf16rn(float f) {
  uint32_t u = __float_as_uint(f);
  uint32_t r = (u + 0x7FFFu + ((u >> 16) & 1u)) >> 16;
  return (unsigned short)r;
}
__device__ __forceinline__ float bf16f(unsigned short h) {
  return __uint_as_float(((uint32_t)h) << 16);
}

// ---------------- Threefry-2x32 (matches jax._src.prng, partitionable) ----------------
__device__ inline void tf2x32(uint32_t k0, uint32_t k1, uint32_t c0, uint32_t c1,
                              uint32_t& o0, uint32_t& o1) {
  uint32_t ks2 = k0 ^ k1 ^ 0x1BD11BDAu;
  uint32_t x0 = c0 + k0, x1 = c1 + k1;
#define TF_R(r) { x0 += x1; x1 = (x1 << (r)) | (x1 >> (32 - (r))); x1 ^= x0; }
  TF_R(13) TF_R(15) TF_R(26) TF_R(6)
  x0 += k1; x1 += ks2 + 1u;
  TF_R(17) TF_R(29) TF_R(16) TF_R(24)
  x0 += ks2; x1 += k0 + 2u;
  TF_R(13) TF_R(15) TF_R(26) TF_R(6)
  x0 += k0; x1 += k1 + 3u;
  TF_R(17) TF_R(29) TF_R(16) TF_R(24)
  x0 += k1; x1 += ks2 + 4u;
  TF_R(13) TF_R(15) TF_R(26) TF_R(6)
  x0 += ks2; x1 += k0 + 5u;
#undef TF_R
  o0 = x0; o1 = x1;
}

__device__ inline void get_round_key(int round, uint32_t& ka, uint32_t& kb) {
  const uint32_t b0 = 0u, b1 = 1u;  // jax.random.key(1) -> (0,1)
  uint32_t K1a, K1b, S1a, S1b;
  tf2x32(b0, b1, 0u, 0u, K1a, K1b);
  tf2x32(b0, b1, 0u, 1u, S1a, S1b);
  if (round == 1) { ka = S1a; kb = S1b; return; }
  uint32_t S2a, S2b;
  tf2x32(K1a, K1b, 0u, 1u, S2a, S2b);
  ka = S2a; kb = S2b;
}

__device__ inline uint32_t gen_key(int round, uint32_t i) {
  uint32_t ka, kb, o0, o1;
  get_round_key(round, ka, kb);
  tf2x32(ka, kb, 0u, i, o0, o1);
  return o0 ^ o1;
}

// ---------------- top-3 (values) + top-2 (indices) primitives ----------------
__device__ __forceinline__ bool gtr(float v1, int k1, float v2, int k2) {
  return (v1 > v2) || (v1 == v2 && k1 < k2);
}
__device__ __forceinline__ void ins3(float& b, float& s, float& t, int& kb, int& ks,
                                     float v, int k) {
  if (gtr(v, k, b, kb))      { t = s; s = b; ks = kb; b = v; kb = k; }
  else if (gtr(v, k, s, ks)) { t = s; s = v; ks = k; }
  else t = fmaxf(t, v);
}
// merge two top-3 sets (disjoint code sets)
__device__ __forceinline__ void mrg3(float& b, float& s, float& t, int& kb, int& ks,
                                     float ob, float os, float ot, int okb, int oks) {
  float nb, ns, m2; int nkb, nks;
  if (gtr(b, kb, ob, okb)) {
    nb = b; nkb = kb;
    if (gtr(s, ks, ob, okb)) { ns = s; nks = ks; m2 = ob; }
    else { ns = ob; nks = okb; m2 = fmaxf(s, os); }
  } else {
    nb = ob; nkb = okb;
    if (gtr(os, oks, b, kb)) { ns = os; nks = oks; m2 = b; }
    else { ns = b; nks = kb; m2 = fmaxf(os, s); }
  }
  t = fmaxf(m2, fmaxf(t, ot));
  b = nb; s = ns; kb = nkb; ks = nks;
}

// ---------------- global_load_lds wrapper (16B) ----------------
__device__ __forceinline__ void gload_lds16(const void* g, void* l) {
  __builtin_amdgcn_global_load_lds(
      (const __attribute__((address_space(1))) uint32_t*)g,
      (__attribute__((address_space(3))) uint32_t*)l, 16, 0, 0);
}

// ---------------- e2[k] = sum(embed[k]^2) ----------------
__global__ void e2_kernel(const float* __restrict__ embed, float* __restrict__ e2) {
  int k = blockIdx.x * blockDim.x + threadIdx.x;
  if (k >= KCB) return;
  const float4* er = (const float4*)(embed + (size_t)k * DIMS);
  float s = 0.f;
  for (int c = 0; c < DIMS / 4; ++c) {
    float4 v = er[c];
    s = fmaf(v.x, v.x, s); s = fmaf(v.y, v.y, s);
    s = fmaf(v.z, v.z, s); s = fmaf(v.w, v.w, s);
  }
  e2[k] = s;
}

// ---------------- split f32 -> bf16 hi + bf16 lo ----------------
__global__ void split_f32(const float* __restrict__ x, unsigned short* __restrict__ hi,
                          unsigned short* __restrict__ lo, int n8) {
  int i = blockIdx.x * blockDim.x + threadIdx.x;
  if (i >= n8) return;
  float4 a = ((const float4*)x)[i * 2];
  float4 b = ((const float4*)x)[i * 2 + 1];
  float v[8] = {a.x, a.y, a.z, a.w, b.x, b.y, b.z, b.w};
  u16x8 h, l;
#pragma unroll
  for (int j = 0; j < 8; ++j) {
    unsigned short hb = bf16rn(v[j]);
    h[j] = hb;
    l[j] = bf16rn(v[j] - bf16f(hb));
  }
  *(u16x8*)&hi[(size_t)i * 8] = h;
  *(u16x8*)&lo[(size_t)i * 8] = l;
}

// ---------------- MFMA distance top-3 ----------------
// score = 2*(xh.eh + xh.el + xl.eh) - e2[k]; 128x256 tile, BK=64, 12 K-steps.
// LDS XOR-swizzle (T2): linear gload_lds dest + inverse-swizzled global src +
// swizzled ds_read addr: byte_in_row ^= ((row&7)<<4).
__global__ __launch_bounds__(256, 2) void dist_mfma(
    const unsigned short* __restrict__ xh, const unsigned short* __restrict__ xl,
    const unsigned short* __restrict__ eh, const unsigned short* __restrict__ el,
    const float* __restrict__ e2,
    float* __restrict__ pb, float* __restrict__ ps, float* __restrict__ pt,
    uint32_t* __restrict__ pkk)
{
  __shared__ short As[128 * 64];   // 16 KB
  __shared__ short Bs[256 * 64];   // 32 KB
  __shared__ float mbv[128], msv[128], mtv[128];
  __shared__ int mkb[128], mks[128];

  const int tid = threadIdx.x;
  const int lane = tid & 63, w = tid >> 6;
  const int wr = w >> 1, wc = w & 1;      // wave tile: 64 rows x 128 cols
  const int l15 = lane & 15, lg = lane >> 4;
  const int n0 = blockIdx.x * 128;   // token tile base
  const int c0 = blockIdx.y * 256;   // code tile base

  f32x4 acc[4][8];
#pragma unroll
  for (int mf = 0; mf < 4; ++mf)
#pragma unroll
    for (int nf = 0; nf < 8; ++nf) acc[mf][nf] = (f32x4){0.f, 0.f, 0.f, 0.f};

#pragma unroll 1
  for (int st = 0; st < 12; ++st) {
    const int p = st >> 2;
    const int d0 = (st & 3) << 6;
    const unsigned short* Ag = (p < 2) ? xh : xl;
    const unsigned short* Bg = (p == 1) ? el : eh;
    __syncthreads();
    // A: 128x64 shorts = 1024 chunks of 16B, 4 issues
#pragma unroll
    for (int i = 0; i < 4; ++i) {
      const int c = i * 256 + tid;
      const int row = c >> 3;
      const int sw = ((c & 7) * 8) ^ ((row & 7) << 3);   // shorts, pre-swizzled src
      gload_lds16(Ag + (size_t)(n0 + row) * DIMS + d0 + sw,
                  (void*)&As[(i * 256 + w * 64) * 8]);
    }
    // B: 256x64 shorts = 2048 chunks, 8 issues
#pragma unroll
    for (int i = 0; i < 8; ++i) {
      const int c = i * 256 + tid;
      const int row = c >> 3;
      const int sw = ((c & 7) * 8) ^ ((row & 7) << 3);
      gload_lds16(Bg + (size_t)(c0 + row) * DIMS + d0 + sw,
                  (void*)&Bs[(i * 256 + w * 64) * 8]);
    }
    __syncthreads();
#pragma unroll
    for (int kk = 0; kk < 2; ++kk) {
      const int kb_ = kk * 32 + lg * 8;   // shorts within row (pre-swizzle)
      bf16x8 af[4], bfv[8];
#pragma unroll
      for (int mf = 0; mf < 4; ++mf) {
        const int row = wr * 64 + mf * 16 + l15;
        af[mf] = *(const bf16x8*)&As[row * 64 + (kb_ ^ ((row & 7) << 3))];
      }
#pragma unroll
      for (int nf = 0; nf < 8; ++nf) {
        const int row = wc * 128 + nf * 16 + l15;
        bfv[nf] = *(const bf16x8*)&Bs[row * 64 + (kb_ ^ ((row & 7) << 3))];
      }
#pragma unroll
      for (int mf = 0; mf < 4; ++mf)
#pragma unroll
        for (int nf = 0; nf < 8; ++nf)
          acc[mf][nf] = __builtin_amdgcn_mfma_f32_16x16x32_bf16(
              af[mf], bfv[nf], acc[mf][nf], 0, 0, 0);
    }
  }

  float e2v[8];
#pragma unroll
  for (int nf = 0; nf < 8; ++nf) e2v[nf] = e2[c0 + wc * 128 + nf * 16 + l15];

  float rb[16], rs[16], rt[16]; int rkb[16], rks[16];
#pragma unroll
  for (int mf = 0; mf < 4; ++mf) {
#pragma unroll
    for (int reg = 0; reg < 4; ++reg) {
      float b = fmaf(2.f, acc[mf][0][reg], -e2v[0]);
      float s = -INFINITY, t = -INFINITY;
      int kb = c0 + wc * 128 + l15, ks = 0x7fffffff;
#pragma unroll
      for (int nf = 1; nf < 8; ++nf) {
        float v = fmaf(2.f, acc[mf][nf][reg], -e2v[nf]);
        ins3(b, s, t, kb, ks, v, c0 + wc * 128 + nf * 16 + l15);
      }
#pragma unroll
      for (int m = 1; m <= 8; m <<= 1) {
        float ob = __shfl_xor(b, m), os = __shfl_xor(s, m), ot = __shfl_xor(t, m);
        int okb = __shfl_xor(kb, m), oks = __shfl_xor(ks, m);
        mrg3(b, s, t, kb, ks, ob, os, ot, okb, oks);
      }
      int q = mf * 4 + reg;
      rb[q] = b; rs[q] = s; rt[q] = t; rkb[q] = kb; rks[q] = ks;
    }
  }

  // wc=1 publishes to LDS, wc=0 merges + writes
  if (wc == 1 && l15 == 0) {
#pragma unroll
    for (int mf = 0; mf < 4; ++mf)
#pragma unroll
      for (int reg = 0; reg < 4; ++reg) {
        int q = mf * 4 + reg;
        int r = wr * 64 + mf * 16 + lg * 4 + reg;
        mbv[r] = rb[q]; msv[r] = rs[q]; mtv[r] = rt[q];
        mkb[r] = rkb[q]; mks[r] = rks[q];
      }
  }
  __syncthreads();
  if (wc == 0 && l15 == 0) {
#pragma unroll
    for (int mf = 0; mf < 4; ++mf)
#pragma unroll
      for (int reg = 0; reg < 4; ++reg) {
        int q = mf * 4 + reg;
        int r = wr * 64 + mf * 16 + lg * 4 + reg;
        float b = rb[q], s = rs[q], t = rt[q];
        int kb = rkb[q], ks = rks[q];
        mrg3(b, s, t, kb, ks, mbv[r], msv[r], mtv[r], mkb[r], mks[r]);
        size_t o = (size_t)blockIdx.y * N_TOK + n0 + r;
        pb[o] = b; ps[o] = s; pt[o] = t;
        pkk[o] = ((uint32_t)kb << 16) | ((uint32_t)ks & 0xffffu);
      }
  }
}

// ---------------- merge 8 column-tile partials + classify ----------------
__global__ void merge8(const float* __restrict__ pb, const float* __restrict__ ps,
                       const float* __restrict__ pt, const uint32_t* __restrict__ pkk,
                       int* __restrict__ ind, int4* __restrict__ pairs,
                       int* __restrict__ listB,
                       uint32_t* __restrict__ cntA, uint32_t* __restrict__ cntB) {
  int n = blockIdx.x * blockDim.x + threadIdx.x;
  if (n >= N_TOK) return;
  float b = pb[n], s = ps[n], t = pt[n];
  uint32_t kk = pkk[n];
  int kb = (int)(kk >> 16), ks = (int)(kk & 0xffffu);
  for (int tt = 1; tt < 8; ++tt) {
    size_t o = (size_t)tt * N_TOK + n;
    uint32_t k2 = pkk[o];
    mrg3(b, s, t, kb, ks, pb[o], ps[o], pt[o], (int)(k2 >> 16), (int)(k2 & 0xffffu));
  }
  ind[n] = kb;
  if (b - s < GAP_THR) {
    if (b - t >= GAP_THR) {
      uint32_t i = atomicAdd(cntA, 1u);
      pairs[i] = make_int4(n, kb, ks, 0);
    } else {
      uint32_t i = atomicAdd(cntB, 1u);
      listB[i] = n;
    }
  }
}

// ---------------- wave-per-row f64 pair decider ----------------
__global__ void refine_pair(const float* __restrict__ x, const float* __restrict__ embed,
                            const int4* __restrict__ pairs, const uint32_t* __restrict__ cntA,
                            int* __restrict__ ind) {
  const uint32_t nA = cntA[0];
  const int lane = threadIdx.x & 63;
  const uint32_t wid = (blockIdx.x * blockDim.x + threadIdx.x) >> 6;
  const uint32_t nw = (gridDim.x * blockDim.x) >> 6;
  for (uint32_t i = wid; i < nA; i += nw) {
    int4 p = pairs[i];
    const int n = p.x, k1 = p.y, k2 = p.z;
    float4 xv = ((const float4*)x)[(size_t)n * 64 + lane];
    float4 a  = ((const float4*)embed)[(size_t)k1 * 64 + lane];
    float4 c  = ((const float4*)embed)[(size_t)k2 * 64 + lane];
    double s1 = 2.0 * ((double)xv.x * a.x + (double)xv.y * a.y
                     + (double)xv.z * a.z + (double)xv.w * a.w)
              - ((double)a.x * a.x + (double)a.y * a.y
               + (double)a.z * a.z + (double)a.w * a.w);
    double s2 = 2.0 * ((double)xv.x * c.x + (double)xv.y * c.y
                     + (double)xv.z * c.z + (double)xv.w * c.w)
              - ((double)c.x * c.x + (double)c.y * c.y
               + (double)c.z * c.z + (double)c.w * c.w);
#pragma unroll
    for (int m = 1; m < 64; m <<= 1) {
      s1 += __shfl_xor(s1, m);
      s2 += __shfl_xor(s2, m);
    }
    if (lane == 0) {
      int wk = (s1 > s2) ? k1 : ((s2 > s1) ? k2 : min(k1, k2));
      ind[n] = wk;
    }
  }
}

// ---------------- full f64 re-scan fallback (rare) ----------------
__global__ void refine_full(const float* __restrict__ x, const float* __restrict__ embed,
                            const int* __restrict__ listB, const uint32_t* __restrict__ cntB,
                            int* __restrict__ ind) {
  __shared__ double xd[DIMS];
  __shared__ double rv[256];
  __shared__ int    rk[256];
  const int tid = threadIdx.x;
  const uint32_t nB = cntB[0];
  for (uint32_t it = blockIdx.x; it < nB; it += gridDim.x) {
    const int n = listB[it];
    __syncthreads();
    xd[tid] = (double)x[(size_t)n * DIMS + tid];
    __syncthreads();
    double bb = -1e300; int bk = 0x7fffffff;
    for (int k = tid; k < KCB; k += 256) {
      const float* er = embed + (size_t)k * DIMS;
      double dot = 0.0, ee = 0.0;
      for (int d = 0; d < DIMS; d += 4) {
        float4 e4 = *(const float4*)(er + d);
        dot += xd[d + 0] * (double)e4.x + xd[d + 1] * (double)e4.y
             + xd[d + 2] * (double)e4.z + xd[d + 3] * (double)e4.w;
        ee  += (double)e4.x * e4.x + (double)e4.y * e4.y
             + (double)e4.z * e4.z + (double)e4.w * e4.w;
      }
      double v = 2.0 * dot - ee;
      if (v > bb || (v == bb && k < bk)) { bb = v; bk = k; }
    }
    rv[tid] = bb; rk[tid] = bk;
    __syncthreads();
    for (int s = 128; s > 0; s >>= 1) {
      if (tid < s) {
        double v2 = rv[tid + s]; int k2 = rk[tid + s];
        if (v2 > rv[tid] || (v2 == rv[tid] && k2 < rk[tid])) { rv[tid] = v2; rk[tid] = k2; }
      }
      __syncthreads();
    }
    if (tid == 0) ind[n] = rk[0];
  }
}

// ---------------- quantize gather + codes + counts + embed_sum ----------------
__global__ void gather_scatter(const float* __restrict__ x, const float* __restrict__ embed,
                               const int* __restrict__ ind,
                               float* __restrict__ outq, float* __restrict__ outcodes,
                               float* __restrict__ counts, float* __restrict__ esum) {
  int idx = blockIdx.x * blockDim.x + threadIdx.x;   // over N_TOK*64 float4s
  if (idx >= N_TOK * 64) return;
  int n = idx >> 6, c = idx & 63;
  int k = ind[n];
  float4 e = ((const float4*)embed)[(size_t)k * 64 + c];
  ((float4*)outq)[idx] = e;
  float4 xv = ((const float4*)x)[idx];
  float* base = esum + (size_t)k * DIMS + c * 4;
  atomicAdd(base + 0, xv.x); atomicAdd(base + 1, xv.y);
  atomicAdd(base + 2, xv.z); atomicAdd(base + 3, xv.w);
  if (c == 0) { outcodes[n] = (float)k; atomicAdd(&counts[k], 1.0f); }
}

// ---------------- new_cluster_size + n-sum + expired ----------------
__global__ void ema_stats(const float* __restrict__ cs, const float* __restrict__ counts,
                          float* __restrict__ out_ncs, int* __restrict__ expired,
                          double* __restrict__ nsum) {
  __shared__ double sd[1024];
  int tid = threadIdx.x;
  double local = 0.0;
  for (int k = tid; k < KCB; k += 1024) {
    double v = 0.99 * (double)cs[k] + 0.01 * (double)counts[k];
    out_ncs[k] = (float)v;
    expired[k] = (v < 2.0) ? 1 : 0;
    local += v;
  }
  sd[tid] = local; __syncthreads();
  for (int s = 512; s > 0; s >>= 1) { if (tid < s) sd[tid] += sd[tid + s]; __syncthreads(); }
  if (tid == 0) nsum[0] = sd[0];
}

// ---------------- new_embed_avg + new_embed ----------------
__global__ void final_embed(const float* __restrict__ x, const float* __restrict__ cs,
                            const float* __restrict__ counts,
                            const float* __restrict__ eavg, const float* __restrict__ esum,
                            const int* __restrict__ expired, const double* __restrict__ nsum,
                            const uint32_t* __restrict__ perm,
                            float* __restrict__ out_eavg, float* __restrict__ out_ne) {
  int idx = blockIdx.x * blockDim.x + threadIdx.x;   // over KCB*64 float4s
  if (idx >= KCB * 64) return;
  int k = idx >> 6, c = idx & 63;
  float4 ea = ((const float4*)eavg)[idx];
  float4 es = ((const float4*)esum)[idx];
  double ax = 0.99 * (double)ea.x + 0.01 * (double)es.x;
  double ay = 0.99 * (double)ea.y + 0.01 * (double)es.y;
  double az = 0.99 * (double)ea.z + 0.01 * (double)es.z;
  double aw = 0.99 * (double)ea.w + 0.01 * (double)es.w;
  float4 nv; nv.x = (float)ax; nv.y = (float)ay; nv.z = (float)az; nv.w = (float)aw;
  ((float4*)out_eavg)[idx] = nv;
  float4 r;
  if (expired[k]) {
    r = ((const float4*)x)[(size_t)perm[k] * 64 + c];
  } else {
    double ncs = 0.99 * (double)cs[k] + 0.01 * (double)counts[k];
    double n = nsum[0];
    double sm = (ncs + 1e-5) / (n + 2048.0 * 1e-5) * n;
    r.x = (float)(ax / sm); r.y = (float)(ay / sm);
    r.z = (float)(az / sm); r.w = (float)(aw / sm);
  }
  ((float4*)out_ne)[idx] = r;
}

// ---------------- permutation pipeline (stable sort by random keys) ----------------
__global__ void keys_round(int round, uint32_t* __restrict__ keys,
                           uint32_t* __restrict__ vals_init, uint32_t* __restrict__ bcount) {
  int i = blockIdx.x * blockDim.x + threadIdx.x;
  if (i >= N_TOK) return;
  uint32_t key = gen_key(round, (uint32_t)i);
  keys[i] = key;
  if (vals_init) vals_init[i] = (uint32_t)i;
  atomicAdd(&bcount[key >> 21], 1u);
}

__global__ void scan2048(const uint32_t* __restrict__ in, uint32_t* __restrict__ out,
                         uint32_t* __restrict__ cursor_zero) {
  __shared__ uint32_t buf[2][2048];
  int t = threadIdx.x;   // 1024
  for (int q = 0; q < 2; ++q) buf[0][t + q * 1024] = in[t + q * 1024];
  cursor_zero[t] = 0; cursor_zero[t + 1024] = 0;
  __syncthreads();
  int src = 0;
  for (int off = 1; off < 2048; off <<= 1) {
    for (int q = 0; q < 2; ++q) {
      int i = t + q * 1024;
      uint32_t v = buf[src][i];
      if (i >= off) v += buf[src][i - off];
      buf[src ^ 1][i] = v;
    }
    src ^= 1; __syncthreads();
  }
  for (int q = 0; q < 2; ++q) {
    int i = t + q * 1024;
    out[i] = buf[src][i] - in[i];   // exclusive
  }
}

__global__ void scatter_buckets(const uint32_t* __restrict__ keys, const uint32_t* __restrict__ vals_in,
                                const uint32_t* __restrict__ bbase, uint32_t* __restrict__ cursor,
                                uint32_t* __restrict__ bkey, uint32_t* __restrict__ bval,
                                uint32_t* __restrict__ bpos) {
  int i = blockIdx.x * blockDim.x + threadIdx.x;
  if (i >= N_TOK) return;
  uint32_t k = keys[i];
  uint32_t b = k >> 21;
  uint32_t p = atomicAdd(&cursor[b], 1u);
  uint32_t s = bbase[b] + p;
  bkey[s] = k; bval[s] = vals_in[i]; bpos[s] = (uint32_t)i;
}

__global__ void rank_buckets(const uint32_t* __restrict__ bkey, const uint32_t* __restrict__ bval,
                             const uint32_t* __restrict__ bpos, const uint32_t* __restrict__ bbase,
                             const uint32_t* __restrict__ bcount, uint32_t* __restrict__ out_vals) {
  int b = blockIdx.x;
  uint32_t base = bbase[b], cnt = bcount[b];
  for (uint32_t t = threadIdx.x; t < cnt; t += blockDim.x) {
    uint32_t k = bkey[base + t], p = bpos[base + t];
    uint32_t r = 0;
    for (uint32_t j = 0; j < cnt; ++j) {
      uint32_t kj = bkey[base + j], pj = bpos[base + j];
      r += (kj < k) | ((kj == k) & (pj < p));
    }
    out_vals[base + r] = bval[base + t];
  }
}

// ---------------- launch ----------------
extern "C" void kernel_launch(void* const* d_in, const int* in_sizes, int n_in,
                              void* d_out, int out_size, void* d_ws, size_t ws_size,
                              hipStream_t stream) {
  const float* x     = (const float*)d_in[0];
  const float* embed = (const float*)d_in[1];
  const float* cs    = (const float*)d_in[2];
  const float* eavg  = (const float*)d_in[3];

  float* out = (float*)d_out;
  float* outQ    = out;                  // 12,288,000
  float* outC    = out + 12288000;       // 48,000
  float* outNCS  = out + 12336000;       // 2,048
  float* outEAVG = out + 12338048;       // 524,288
  float* outNE   = out + 12862336;       // 524,288

  char* w = (char*)d_ws;
  size_t off = 0;
  auto alloc = [&](size_t bytes) -> void* {
    void* p = w + off; off += (bytes + 255) & ~(size_t)255; return p;
  };
  unsigned short* xh = (unsigned short*)alloc((size_t)N_TOK * DIMS * 2);
  unsigned short* xl = (unsigned short*)alloc((size_t)N_TOK * DIMS * 2);
  unsigned short* eh = (unsigned short*)alloc((size_t)KCB * DIMS * 2);
  unsigned short* el = (unsigned short*)alloc((size_t)KCB * DIMS * 2);
  float*    e2      = (float*)alloc(KCB * 4);
  float*    counts  = (float*)alloc(KCB * 4);
  float*    esum    = (float*)alloc((size_t)KCB * DIMS * 4);   // contiguous after counts
  float*    pbest   = (float*)alloc((size_t)8 * N_TOK * 4);
  float*    psecond = (float*)alloc((size_t)8 * N_TOK * 4);
  float*    pthird  = (float*)alloc((size_t)8 * N_TOK * 4);
  uint32_t* pkk     = (uint32_t*)alloc((size_t)8 * N_TOK * 4);
  int*      ind     = (int*)alloc(N_TOK * 4);
  int4*     pairs   = (int4*)alloc((size_t)N_TOK * 16);
  int*      listB   = (int*)alloc(N_TOK * 4);
  uint32_t* cntAB   = (uint32_t*)alloc(256);      // [0]=cntA, [1]=cntB
  double*   nsum    = (double*)alloc(256);
  int*      expired = (int*)alloc(KCB * 4);
  uint32_t* keys    = (uint32_t*)alloc(N_TOK * 4);
  uint32_t* valsA   = (uint32_t*)alloc(N_TOK * 4);
  uint32_t* bkey    = (uint32_t*)alloc(N_TOK * 4);
  uint32_t* bval    = (uint32_t*)alloc(N_TOK * 4);
  uint32_t* bpos    = (uint32_t*)alloc(N_TOK * 4);
  uint32_t* valsB   = (uint32_t*)alloc(N_TOK * 4);
  uint32_t* bcount  = (uint32_t*)alloc(KCB * 4);
  uint32_t* bbase   = (uint32_t*)alloc(KCB * 4);
  uint32_t* cursor  = (uint32_t*)alloc(KCB * 4);

  // zero accumulators (counts+esum contiguous), tie counters, bucket counts
  hipMemsetAsync(counts, 0, KCB * 4 + (size_t)KCB * DIMS * 4, stream);
  hipMemsetAsync(cntAB, 0, 256, stream);
  hipMemsetAsync(bcount, 0, KCB * 4, stream);

  e2_kernel<<<8, 256, 0, stream>>>(embed, e2);
  split_f32<<<6000, 256, 0, stream>>>(x, xh, xl, N_TOK * DIMS / 8);
  split_f32<<<256, 256, 0, stream>>>(embed, eh, el, KCB * DIMS / 8);

  dist_mfma<<<dim3(375, 8), 256, 0, stream>>>(xh, xl, eh, el, e2,
                                              pbest, psecond, pthird, pkk);
  merge8<<<188, 256, 0, stream>>>(pbest, psecond, pthird, pkk,
                                  ind, pairs, listB, &cntAB[0], &cntAB[1]);
  refine_pair<<<128, 256, 0, stream>>>(x, embed, pairs, &cntAB[0], ind);
  refine_full<<<64, 256, 0, stream>>>(x, embed, listB, &cntAB[1], ind);

  gather_scatter<<<12000, 256, 0, stream>>>(x, embed, ind, outQ, outC, counts, esum);
  ema_stats<<<1, 1024, 0, stream>>>(cs, counts, outNCS, expired, nsum);

  // permutation: round 1 (vals = iota)
  keys_round<<<188, 256, 0, stream>>>(1, keys, valsA, bcount);
  scan2048<<<1, 1024, 0, stream>>>(bcount, bbase, cursor);
  scatter_buckets<<<188, 256, 0, stream>>>(keys, valsA, bbase, cursor, bkey, bval, bpos);
  rank_buckets<<<2048, 64, 0, stream>>>(bkey, bval, bpos, bbase, bcount, valsB);
  // round 2 (vals = round-1 output)
  hipMemsetAsync(bcount, 0, KCB * 4, stream);
  keys_round<<<188, 256, 0, stream>>>(2, keys, nullptr, bcount);
  scan2048<<<1, 1024, 0, stream>>>(bcount, bbase, cursor);
  scatter_buckets<<<188, 256, 0, stream>>>(keys, valsB, bbase, cursor, bkey, bval, bpos);
  rank_buckets<<<2048, 64, 0, stream>>>(bkey, bval, bpos, bbase, bcount, valsA);

  final_embed<<<512, 256, 0, stream>>>(x, cs, counts, eavg, esum, expired, nsum,
                                       valsA, outEAVG, outNE);
}